// Round 11
// baseline (445.237 us; speedup 1.0000x reference)
//
#include <hip/hip_runtime.h>
#include <hip/hip_bf16.h>

#define QN 150
#define CN 512
#define HWN 441
#define WAYN 5
#define SHOTN 5
#define NSAMP 2205           // SHOT*HW
#define MROWS (QN * HWN)     // 66150 packed rows
#define MT256 259            // ceil(66150/256)
#define MPAD2 (MT256 * 256)  // 66304
#define KP 2208              // cov K padded (32*69)
#define KPB (KP * 2)         // row bytes of x2c

typedef unsigned short u16;
typedef unsigned int u32;
typedef __attribute__((ext_vector_type(8))) short short8;
typedef __attribute__((ext_vector_type(4))) float f32x4;

__device__ __forceinline__ u16 f2b(float f) {
    return __builtin_bit_cast(u16, __float2bfloat16(f));
}
__device__ __forceinline__ float b2f(u16 h) {
    u32 u = ((u32)h) << 16;
    return __builtin_bit_cast(float, u);
}

__device__ __forceinline__ void gload16(const void* g, void* l) {
    __builtin_amdgcn_global_load_lds(
        (const __attribute__((address_space(1))) unsigned int*)g,
        (__attribute__((address_space(3))) unsigned int*)l, 16, 0, 0);
}

// pair index p in [0,10) -> (lo, hi) with lo <= hi over 4 blocks of 128
__device__ __forceinline__ void pair_decode(int p, int& lo, int& hi) {
    hi = (p >= 6) ? 3 : (p >= 3 ? 2 : (p >= 1 ? 1 : 0));
    int tri = (hi == 3) ? 6 : (hi == 2 ? 3 : (hi == 1 ? 1 : 0));
    lo = p - tri;
}

// ---------------- fused: per-(way,channel) mean + center x2 -> bf16 x2c[w][c][k] ----------------
__global__ void wx2c_kernel(const float* __restrict__ x2, u16* __restrict__ x2c) {
    int b = blockIdx.x;             // w*512 + c
    int w = b >> 9, c = b & 511;
    int lane = threadIdx.x;         // 64
    float s = 0.f;
    #pragma unroll
    for (int sh = 0; sh < SHOTN; ++sh) {
        const float* p = x2 + ((size_t)((w * SHOTN + sh) * CN + c)) * HWN;
        for (int i = lane; i < HWN; i += 64) s += p[i];
    }
    #pragma unroll
    for (int off = 32; off > 0; off >>= 1) s += __shfl_down(s, off);
    float m = __shfl(s, 0) * (1.0f / NSAMP);

    u16* dst = x2c + ((size_t)(w * CN + c)) * KP;
    #pragma unroll
    for (int sh = 0; sh < SHOTN; ++sh) {
        const float* p = x2 + ((size_t)((w * SHOTN + sh) * CN + c)) * HWN;
        for (int i = lane; i < HWN; i += 64) dst[sh * HWN + i] = f2b(p[i] - m);
    }
    if (lane < (KP - NSAMP)) dst[NSAMP + lane] = 0;
}

// ---------------- cov MFMA split-K, lower-triangle blocks only ----------------
// grid (10, 1, 15): x = block-pair (cblk>=dblk), z = w*3 + ksp; K=736 per block
__global__ __launch_bounds__(256, 2) void covmfma_kernel(const u16* __restrict__ x2c,
                                                         float* __restrict__ covf) {
    __shared__ __align__(16) u16 As[2][128 * 32];
    __shared__ __align__(16) u16 Bs[2][128 * 32];
    int z  = blockIdx.z;
    int w  = z / 3, ksp = z - w * 3;
    int dblk, cblk;
    pair_decode(blockIdx.x, dblk, cblk);    // cblk >= dblk
    int c0 = cblk * 128;
    int d0 = dblk * 128;
    int t = threadIdx.x;
    int lane = t & 63, wid = t >> 6;
    int wr = wid >> 1, wc = wid & 1;
    int rl = lane & 15, g4 = lane >> 4;
    int swz = ((rl >> 1) & 3) << 4;
    int s0 = wid * 2048 + lane * 16;

    const char* gX = (const char*)(x2c + (size_t)w * CN * KP) + ksp * 1472; // 736 elems

    f32x4 acc[4][4];
    #pragma unroll
    for (int mi = 0; mi < 4; ++mi)
        #pragma unroll
        for (int ni = 0; ni < 4; ++ni)
            acc[mi][ni] = (f32x4){0.f, 0.f, 0.f, 0.f};

    int buf = 0;
    #pragma unroll
    for (int j = 0; j < 2; ++j) {
        int s = s0 + j * 1024;
        int row = s >> 6, kbs = (s & 63) ^ (((row >> 1) & 3) << 4);
        gload16(gX + (size_t)(c0 + row) * KPB + kbs, (char*)&As[0][0] + wid * 2048 + j * 1024);
        gload16(gX + (size_t)(d0 + row) * KPB + kbs, (char*)&Bs[0][0] + wid * 2048 + j * 1024);
    }
    __syncthreads();

    for (int ks = 0; ks < 23; ++ks) {
        if (ks < 22) {
            int koff = (ks + 1) * 64;
            #pragma unroll
            for (int j = 0; j < 2; ++j) {
                int s = s0 + j * 1024;
                int row = s >> 6, kbs = (s & 63) ^ (((row >> 1) & 3) << 4);
                gload16(gX + (size_t)(c0 + row) * KPB + koff + kbs,
                        (char*)&As[buf ^ 1][0] + wid * 2048 + j * 1024);
                gload16(gX + (size_t)(d0 + row) * KPB + koff + kbs,
                        (char*)&Bs[buf ^ 1][0] + wid * 2048 + j * 1024);
            }
        }
        const char* Ab = (const char*)&As[buf][0];
        const char* Bb = (const char*)&Bs[buf][0];
        int kread = (g4 * 16) ^ swz;
        short8 a[4], b[4];
        #pragma unroll
        for (int mi = 0; mi < 4; ++mi)
            a[mi] = *(const short8*)(Ab + (wr * 64 + mi * 16 + rl) * 64 + kread);
        #pragma unroll
        for (int ni = 0; ni < 4; ++ni)
            b[ni] = *(const short8*)(Bb + (wc * 64 + ni * 16 + rl) * 64 + kread);
        #pragma unroll
        for (int mi = 0; mi < 4; ++mi)
            #pragma unroll
            for (int ni = 0; ni < 4; ++ni)
                acc[mi][ni] = __builtin_amdgcn_mfma_f32_16x16x32_bf16(
                    a[mi], b[ni], acc[mi][ni], 0, 0, 0);
        __syncthreads();
        buf ^= 1;
    }

    const float inv = 1.0f / (NSAMP - 1);
    #pragma unroll
    for (int mi = 0; mi < 4; ++mi)
        #pragma unroll
        for (int r = 0; r < 4; ++r) {
            int c = c0 + wr * 64 + mi * 16 + g4 * 4 + r;
            #pragma unroll
            for (int ni = 0; ni < 4; ++ni) {
                int d = d0 + wc * 64 + ni * 16 + rl;
                atomicAdd(&covf[((size_t)w * CN + c) * CN + d], acc[mi][ni][r] * inv);
            }
        }
}

// ---------------- covf -> covb bf16 ----------------
__global__ void cov2b_kernel(const float* __restrict__ covf, u16* __restrict__ covb) {
    int i = blockIdx.x * 256 + threadIdx.x;
    covb[i] = f2b(covf[i]);
}

// ---------------- transpose+center x1 -> Abf[(q*441+i)][c] bf16 (packed rows) ----------------
__global__ __launch_bounds__(256) void qtrans_kernel(const float* __restrict__ x1,
                                                     u16* __restrict__ Abf) {
    __shared__ u16 S[512][72];
    __shared__ float qm[64];
    int c0 = blockIdx.x * 64;
    int q  = blockIdx.y;
    int t = threadIdx.x;
    int lane = t & 63, cq = t >> 6;

    for (int cc = cq; cc < 64; cc += 4) {
        int c = c0 + cc;
        const float* p = x1 + ((size_t)q * CN + c) * HWN;
        float s = 0.f;
        for (int ic = 0; ic < 8; ++ic) {
            int i = ic * 64 + lane;
            float v = (i < HWN) ? p[i] : 0.f;
            s += v;
            S[i][cc] = f2b(v);
        }
        #pragma unroll
        for (int off = 32; off > 0; off >>= 1) s += __shfl_down(s, off);
        if (lane == 0) qm[cc] = s * (1.0f / HWN);
    }
    __syncthreads();

    int coct = t & 7;
    for (int p = 0; p < 16; ++p) {
        int il = p * 32 + (t >> 3);
        if (il >= HWN) continue;
        short8 v = *(const short8*)(&S[il][coct * 8]);
        short8 o;
        #pragma unroll
        for (int j = 0; j < 8; ++j) {
            float f = b2f((u16)v[j]) - qm[coct * 8 + j];
            o[j] = (short)f2b(f);
        }
        *(short8*)(Abf + ((size_t)(q * HWN + il)) * CN + c0 + coct * 8) = o;
    }
}

// ---------------- init: zero simws + covf + Abf pad rows ----------------
__global__ void init2_kernel(float* __restrict__ simws, float* __restrict__ covf,
                             u32* __restrict__ AbfPad32) {
    int tid = blockIdx.x * blockDim.x + threadIdx.x;
    int stride = gridDim.x * blockDim.x;
    int nsim = WAYN * MPAD2;
    for (int i = tid; i < nsim; i += stride) simws[i] = 0.f;
    int ncov = WAYN * CN * CN;
    for (int i = tid; i < ncov; i += stride) covf[i] = 0.f;
    int npadw = (MPAD2 - MROWS) * CN / 2;
    for (int i = tid; i < npadw; i += stride) AbfPad32[i] = 0;
}

// ---------------- main: block-symmetric quadratic form ----------------
// q^T C q = sum_b q_b^T C_bb q_b + 2 sum_{b1<b2} q_b1^T C_b1b2 q_b2  (10 of 16 blocks).
// Per block: M=256 rows x N=128 (d in b2) x K=128 (c in b1). 256 thr = 4 waves (2M x 2N),
// wave tile 128x64, acc[8][4]=128 AGPR, ring-2 LDS 48 KiB static -> 2 blocks/CU (m114 overlap).
// B[d][k=c] = covb[d][c], lower-triangle block (b2,b1). Merged r10 chunk body, depth-1 prefetch.
__global__ __launch_bounds__(256, 2) void gemmT_kernel(const u16* __restrict__ Abf,
                                                       const u16* __restrict__ covb,
                                                       float* __restrict__ simws) {
    __shared__ __align__(16) char smem[2][24576];   // slot: A 16KB + B 8KB

    int x = blockIdx.x & 7;
    int l = blockIdx.x >> 3;
    int m = x * 33 + l / 50;
    if (m >= MT256) return;
    int inner = l - (l / 50) * 50;
    int w = inner % 5;
    int p = inner / 5;
    int b1, b2;
    pair_decode(p, b1, b2);          // b1 <= b2
    int r0 = m * 256;

    int t = threadIdx.x;
    int lane = t & 63, wid = t >> 6;
    int wr = wid >> 1, wc = wid & 1;        // 2M x 2N waves
    int rl = lane & 15, g4 = lane >> 4;
    int swz = ((rl >> 1) & 3) << 4;

    const char* gA = (const char*)(Abf + (size_t)r0 * CN);   // row stride 1024 B; + b1*256 col bytes
    const char* gB = (const char*)(covb + ((size_t)w * CN + b2 * 128) * CN + b1 * 128);

    f32x4 acc[8][4];
    #pragma unroll
    for (int mi = 0; mi < 8; ++mi)
        #pragma unroll
        for (int ni = 0; ni < 4; ++ni)
            acc[mi][ni] = (f32x4){0.f, 0.f, 0.f, 0.f};

    // stage chunk kc (K=32 slice) into slot kc&1: A 4 + B 2 gload16 per thread
    auto stage_chunk = [&](int kc) {
        char* sl = smem[kc & 1];
        int kbyte = kc * 64;
        #pragma unroll
        for (int j = 0; j < 4; ++j) {
            int off = j * 4096 + t * 16;
            int row = off >> 6;
            int kbs = (off & 63) ^ (((row >> 1) & 3) << 4);
            gload16(gA + (size_t)row * 1024 + b1 * 256 + kbyte + kbs, sl + off);
        }
        #pragma unroll
        for (int j = 0; j < 2; ++j) {
            int off = j * 4096 + t * 16;
            int row = off >> 6;
            int kbs = (off & 63) ^ (((row >> 1) & 3) << 4);
            gload16(gB + (size_t)row * 1024 + kbyte + kbs, sl + 16384 + off);
        }
    };

    // merged chunk: 12 ds_reads (b first) + 32 MFMA
    auto do_chunk = [&](int c) {
        const char* Ab = smem[c & 1];
        const char* Bb = smem[c & 1] + 16384;
        int kread = (g4 * 16) ^ swz;
        short8 a[8], b[4];
        #pragma unroll
        for (int ni = 0; ni < 4; ++ni) {
            b[ni] = *(const short8*)(Bb + (wc * 64 + ni * 16 + rl) * 64 + kread);
            a[ni] = *(const short8*)(Ab + (wr * 128 + ni * 16 + rl) * 64 + kread);
        }
        #pragma unroll
        for (int mi = 4; mi < 8; ++mi)
            a[mi] = *(const short8*)(Ab + (wr * 128 + mi * 16 + rl) * 64 + kread);
        __builtin_amdgcn_s_setprio(1);
        #pragma unroll
        for (int mi = 0; mi < 8; ++mi)
            #pragma unroll
            for (int ni = 0; ni < 4; ++ni)
                acc[mi][ni] = __builtin_amdgcn_mfma_f32_16x16x32_bf16(
                    a[mi], b[ni], acc[mi][ni], 0, 0, 0);
        __builtin_amdgcn_s_setprio(0);
        // reads retired before this wave's MFMAs issued -> next top barrier closes the slot
    };

    stage_chunk(0);

    #pragma unroll 1
    for (int c = 0; c < 4; ++c) {
        asm volatile("s_waitcnt vmcnt(0)" ::: "memory");   // chunk-c loads landed (covered by prev chunk)
        __builtin_amdgcn_s_barrier();
        asm volatile("" ::: "memory");
        if (c < 3) stage_chunk(c + 1);                     // depth-1 prefetch into other slot
        do_chunk(c);
    }

    // epilogue: sim partial over this block's 128 d-columns; weight 2 for off-diagonal pairs
    __syncthreads();
    float* simpart = (float*)smem;      // [256][3] stride-3 -> conflict-free
    #pragma unroll
    for (int mi = 0; mi < 8; ++mi) {
        #pragma unroll
        for (int r = 0; r < 4; ++r) {
            int Rl = wr * 128 + mi * 16 + g4 * 4 + r;
            size_t Rg = (size_t)r0 + Rl;
            float s = 0.f;
            #pragma unroll
            for (int ni = 0; ni < 4; ++ni) {
                int d = b2 * 128 + wc * 64 + ni * 16 + rl;
                s += acc[mi][ni][r] * b2f(Abf[Rg * CN + d]);
            }
            s += __shfl_xor(s, 1);
            s += __shfl_xor(s, 2);
            s += __shfl_xor(s, 4);
            s += __shfl_xor(s, 8);
            if (rl == 0) simpart[Rl * 3 + wc] = s;
        }
    }
    __syncthreads();
    {
        float v = simpart[t * 3 + 0] + simpart[t * 3 + 1];
        if (b1 != b2) v *= 2.f;
        atomicAdd(&simws[(size_t)w * MPAD2 + r0 + t], v);
    }
}

// ---------------- finish: act + conv dot + bias -> scores ----------------
__global__ void finish_kernel(const float* __restrict__ simws,
                              const float* __restrict__ conv_w,
                              const float* __restrict__ conv_b,
                              float* __restrict__ scores) {
    int q = blockIdx.x, w = blockIdx.y;
    int t = threadIdx.x;    // 128
    const float* sp = simws + (size_t)w * MPAD2 + q * HWN;
    float s = 0.f;
    for (int i = t; i < HWN; i += 128) {
        float v = sp[i];
        float a = (v >= 0.f) ? v : 0.2f * v;
        s += a * conv_w[i];
    }
    __shared__ float red[2];
    #pragma unroll
    for (int off = 32; off > 0; off >>= 1) s += __shfl_down(s, off);
    if ((t & 63) == 0) red[t >> 6] = s;
    __syncthreads();
    if (t == 0) scores[q * WAYN + w] = red[0] + red[1] + conv_b[0];
}

extern "C" void kernel_launch(void* const* d_in, const int* in_sizes, int n_in,
                              void* d_out, int out_size, void* d_ws, size_t ws_size,
                              hipStream_t stream) {
    const float* x1     = (const float*)d_in[0];
    const float* x2     = (const float*)d_in[1];
    const float* conv_w = (const float*)d_in[2];
    const float* conv_b = (const float*)d_in[3];
    float* scores = (float*)d_out;

    char* ws = (char*)d_ws;
    u16* covb    = (u16*)ws;                               // 2,621,440 B
    float* simws = (float*)(ws + 2631680);                 // 1,326,080 B
    float* covf  = (float*)(ws + 3957760);                 // 5,242,880 B
    // x2c aliases head of Abf (covmfma reads x2c before qtrans writes Abf)
    u16* x2c     = (u16*)(ws + 9200640);                   // 11,304,960 B
    u16* Abf     = (u16*)(ws + 9200640);                   // 66304*512*2 = 67,895,296 B

    wx2c_kernel<<<WAYN * CN, 64, 0, stream>>>(x2, x2c);
    init2_kernel<<<256, 256, 0, stream>>>(simws, covf, (u32*)(Abf + (size_t)MROWS * CN));
    covmfma_kernel<<<dim3(10, 1, WAYN * 3), 256, 0, stream>>>(x2c, covf);
    cov2b_kernel<<<WAYN * CN * CN / 256, 256, 0, stream>>>(covf, covb);
    qtrans_kernel<<<dim3(8, QN), 256, 0, stream>>>(x1, Abf);
    gemmT_kernel<<<8 * 33 * 50, 256, 0, stream>>>(Abf, covb, simws);
    finish_kernel<<<dim3(QN, WAYN), 128, 0, stream>>>(simws, conv_w, conv_b, scores);
}

// Round 12
// 367.634 us; speedup vs baseline: 1.2111x; 1.2111x over previous
//
#include <hip/hip_runtime.h>
#include <hip/hip_bf16.h>

#define QN 150
#define CN 512
#define HWN 441
#define WAYN 5
#define SHOTN 5
#define NSAMP 2205           // SHOT*HW
#define MROWS (QN * HWN)     // 66150 packed rows
#define MT256 259            // ceil(66150/256)
#define MPAD2 (MT256 * 256)  // 66304
#define KP 2208              // cov K padded (32*69)
#define KPB (KP * 2)         // row bytes of x2c

typedef unsigned short u16;
typedef unsigned int u32;
typedef __attribute__((ext_vector_type(8))) short short8;
typedef __attribute__((ext_vector_type(4))) float f32x4;

__device__ __forceinline__ u16 f2b(float f) {
    return __builtin_bit_cast(u16, __float2bfloat16(f));
}
__device__ __forceinline__ float b2f(u16 h) {
    u32 u = ((u32)h) << 16;
    return __builtin_bit_cast(float, u);
}

__device__ __forceinline__ void gload16(const void* g, void* l) {
    __builtin_amdgcn_global_load_lds(
        (const __attribute__((address_space(1))) unsigned int*)g,
        (__attribute__((address_space(3))) unsigned int*)l, 16, 0, 0);
}

// pair index p in [0,10) -> (lo, hi) with lo <= hi over 4 blocks of 128
__device__ __forceinline__ void pair_decode(int p, int& lo, int& hi) {
    hi = (p >= 6) ? 3 : (p >= 3 ? 2 : (p >= 1 ? 1 : 0));
    int tri = (hi == 3) ? 6 : (hi == 2 ? 3 : (hi == 1 ? 1 : 0));
    lo = p - tri;
}

// ---------------- fused: per-(way,channel) mean + center x2 -> bf16 x2c[w][c][k] ----------------
__global__ void wx2c_kernel(const float* __restrict__ x2, u16* __restrict__ x2c) {
    int b = blockIdx.x;             // w*512 + c
    int w = b >> 9, c = b & 511;
    int lane = threadIdx.x;         // 64
    float s = 0.f;
    #pragma unroll
    for (int sh = 0; sh < SHOTN; ++sh) {
        const float* p = x2 + ((size_t)((w * SHOTN + sh) * CN + c)) * HWN;
        for (int i = lane; i < HWN; i += 64) s += p[i];
    }
    #pragma unroll
    for (int off = 32; off > 0; off >>= 1) s += __shfl_down(s, off);
    float m = __shfl(s, 0) * (1.0f / NSAMP);

    u16* dst = x2c + ((size_t)(w * CN + c)) * KP;
    #pragma unroll
    for (int sh = 0; sh < SHOTN; ++sh) {
        const float* p = x2 + ((size_t)((w * SHOTN + sh) * CN + c)) * HWN;
        for (int i = lane; i < HWN; i += 64) dst[sh * HWN + i] = f2b(p[i] - m);
    }
    if (lane < (KP - NSAMP)) dst[NSAMP + lane] = 0;
}

// ---------------- cov MFMA split-K, lower-triangle 128-blocks only ----------------
// grid (10, 1, 15): x = block-pair (cblk>=dblk), z = w*3 + ksp; K=736 per block
__global__ __launch_bounds__(256, 2) void covmfma_kernel(const u16* __restrict__ x2c,
                                                         float* __restrict__ covf) {
    __shared__ __align__(16) u16 As[2][128 * 32];
    __shared__ __align__(16) u16 Bs[2][128 * 32];
    int z  = blockIdx.z;
    int w  = z / 3, ksp = z - w * 3;
    int dblk, cblk;
    pair_decode(blockIdx.x, dblk, cblk);    // cblk >= dblk
    int c0 = cblk * 128;
    int d0 = dblk * 128;
    int t = threadIdx.x;
    int lane = t & 63, wid = t >> 6;
    int wr = wid >> 1, wc = wid & 1;
    int rl = lane & 15, g4 = lane >> 4;
    int swz = ((rl >> 1) & 3) << 4;
    int s0 = wid * 2048 + lane * 16;

    const char* gX = (const char*)(x2c + (size_t)w * CN * KP) + ksp * 1472; // 736 elems

    f32x4 acc[4][4];
    #pragma unroll
    for (int mi = 0; mi < 4; ++mi)
        #pragma unroll
        for (int ni = 0; ni < 4; ++ni)
            acc[mi][ni] = (f32x4){0.f, 0.f, 0.f, 0.f};

    int buf = 0;
    #pragma unroll
    for (int j = 0; j < 2; ++j) {
        int s = s0 + j * 1024;
        int row = s >> 6, kbs = (s & 63) ^ (((row >> 1) & 3) << 4);
        gload16(gX + (size_t)(c0 + row) * KPB + kbs, (char*)&As[0][0] + wid * 2048 + j * 1024);
        gload16(gX + (size_t)(d0 + row) * KPB + kbs, (char*)&Bs[0][0] + wid * 2048 + j * 1024);
    }
    __syncthreads();

    for (int ks = 0; ks < 23; ++ks) {
        if (ks < 22) {
            int koff = (ks + 1) * 64;
            #pragma unroll
            for (int j = 0; j < 2; ++j) {
                int s = s0 + j * 1024;
                int row = s >> 6, kbs = (s & 63) ^ (((row >> 1) & 3) << 4);
                gload16(gX + (size_t)(c0 + row) * KPB + koff + kbs,
                        (char*)&As[buf ^ 1][0] + wid * 2048 + j * 1024);
                gload16(gX + (size_t)(d0 + row) * KPB + koff + kbs,
                        (char*)&Bs[buf ^ 1][0] + wid * 2048 + j * 1024);
            }
        }
        const char* Ab = (const char*)&As[buf][0];
        const char* Bb = (const char*)&Bs[buf][0];
        int kread = (g4 * 16) ^ swz;
        short8 a[4], b[4];
        #pragma unroll
        for (int mi = 0; mi < 4; ++mi)
            a[mi] = *(const short8*)(Ab + (wr * 64 + mi * 16 + rl) * 64 + kread);
        #pragma unroll
        for (int ni = 0; ni < 4; ++ni)
            b[ni] = *(const short8*)(Bb + (wc * 64 + ni * 16 + rl) * 64 + kread);
        #pragma unroll
        for (int mi = 0; mi < 4; ++mi)
            #pragma unroll
            for (int ni = 0; ni < 4; ++ni)
                acc[mi][ni] = __builtin_amdgcn_mfma_f32_16x16x32_bf16(
                    a[mi], b[ni], acc[mi][ni], 0, 0, 0);
        __syncthreads();
        buf ^= 1;
    }

    const float inv = 1.0f / (NSAMP - 1);
    #pragma unroll
    for (int mi = 0; mi < 4; ++mi)
        #pragma unroll
        for (int r = 0; r < 4; ++r) {
            int c = c0 + wr * 64 + mi * 16 + g4 * 4 + r;
            #pragma unroll
            for (int ni = 0; ni < 4; ++ni) {
                int d = d0 + wc * 64 + ni * 16 + rl;
                atomicAdd(&covf[((size_t)w * CN + c) * CN + d], acc[mi][ni][r] * inv);
            }
        }
}

// ---------------- covf (lower-triangle blocks) -> covb bf16, symmetrized full ----------------
__global__ void cov2b_kernel(const float* __restrict__ covf, u16* __restrict__ covb) {
    int i = blockIdx.x * 256 + threadIdx.x;        // w*CN*CN + c*CN + d
    int w = i >> 18;
    int cd = i & ((1 << 18) - 1);
    int c = cd >> 9, d = cd & 511;
    int cb = c >> 7, db = d >> 7;
    size_t src;
    if (cb >= db) src = ((size_t)w << 18) + ((size_t)c << 9) + d;
    else          src = ((size_t)w << 18) + ((size_t)d << 9) + c;   // mirror from lower block
    covb[i] = f2b(covf[src]);
}

// ---------------- transpose+center x1 -> Abf[(q*441+i)][c] bf16 (packed rows) ----------------
__global__ __launch_bounds__(256) void qtrans_kernel(const float* __restrict__ x1,
                                                     u16* __restrict__ Abf) {
    __shared__ u16 S[512][72];
    __shared__ float qm[64];
    int c0 = blockIdx.x * 64;
    int q  = blockIdx.y;
    int t = threadIdx.x;
    int lane = t & 63, cq = t >> 6;

    for (int cc = cq; cc < 64; cc += 4) {
        int c = c0 + cc;
        const float* p = x1 + ((size_t)q * CN + c) * HWN;
        float s = 0.f;
        for (int ic = 0; ic < 8; ++ic) {
            int i = ic * 64 + lane;
            float v = (i < HWN) ? p[i] : 0.f;
            s += v;
            S[i][cc] = f2b(v);
        }
        #pragma unroll
        for (int off = 32; off > 0; off >>= 1) s += __shfl_down(s, off);
        if (lane == 0) qm[cc] = s * (1.0f / HWN);
    }
    __syncthreads();

    int coct = t & 7;
    for (int p = 0; p < 16; ++p) {
        int il = p * 32 + (t >> 3);
        if (il >= HWN) continue;
        short8 v = *(const short8*)(&S[il][coct * 8]);
        short8 o;
        #pragma unroll
        for (int j = 0; j < 8; ++j) {
            float f = b2f((u16)v[j]) - qm[coct * 8 + j];
            o[j] = (short)f2b(f);
        }
        *(short8*)(Abf + ((size_t)(q * HWN + il)) * CN + c0 + coct * 8) = o;
    }
}

// ---------------- init: zero simws + covf + Abf pad rows ----------------
__global__ void init2_kernel(float* __restrict__ simws, float* __restrict__ covf,
                             u32* __restrict__ AbfPad32) {
    int tid = blockIdx.x * blockDim.x + threadIdx.x;
    int stride = gridDim.x * blockDim.x;
    int nsim = WAYN * MPAD2;
    for (int i = tid; i < nsim; i += stride) simws[i] = 0.f;
    int ncov = WAYN * CN * CN;
    for (int i = tid; i < ncov; i += stride) covf[i] = 0.f;
    int npadw = (MPAD2 - MROWS) * CN / 2;
    for (int i = tid; i < npadw; i += stride) AbfPad32[i] = 0;
}

// ---------------- main: 256-granularity block-symmetric quadratic form on the r10 structure ----------------
// sim = q0^T C00 q0 + q1^T C11 q1 + 2 q0^T C01 q1 : 3 pairs x K=256 (0.75x FLOPs).
// Per block: M=256 x N=256 (d in half b2) x K=256 (c in half b1), 8 chunks of 32.
// 512 thr = 8 waves (2M x 4N), wave out 128x64, ring-4 LDS 128 KiB, merged chunk body (r10),
// counted vmcnt(8) discipline, 1 barrier/chunk. 1 block/CU (r8's register envelope).
__global__ __launch_bounds__(512, 2) void gemm256_kernel(const u16* __restrict__ Abf,
                                                         const u16* __restrict__ covb,
                                                         float* __restrict__ simws) {
    extern __shared__ char smem[];

    int x = blockIdx.x & 7;
    int l = blockIdx.x >> 3;
    int m = x * 33 + l / 15;
    if (m >= MT256) return;
    int inner = l - (l / 15) * 15;     // 15 blocks (3 pairs x 5 ways) share the A m-tile's XCD
    int w = inner % 5;
    int p = inner / 5;                 // 0:(0,0) 1:(1,1) 2:(0,1)
    int b1 = (p == 1) ? 1 : 0;         // K half (c)
    int b2 = (p == 0) ? 0 : 1;         // N half (d)
    int r0 = m * 256;

    int t = threadIdx.x;
    int lane = t & 63, wid = t >> 6;
    int wr = wid >> 2, wc = wid & 3;        // 2M x 4N waves
    int rl = lane & 15, g4 = lane >> 4;
    int swz = ((rl >> 1) & 3) << 4;

    const char* gA = (const char*)(Abf + (size_t)r0 * CN) + b1 * 512;            // row stride 1024 B
    const char* gB = (const char*)(covb + ((size_t)w * CN + b2 * 256) * CN) + b1 * 512;

    f32x4 acc[8][4];
    #pragma unroll
    for (int mi = 0; mi < 8; ++mi)
        #pragma unroll
        for (int ni = 0; ni < 4; ++ni)
            acc[mi][ni] = (f32x4){0.f, 0.f, 0.f, 0.f};

    // stage half (j=0/1) of chunk kc into ring slot kc&3: one A + one B gload16 per thread
    auto stage_pair = [&](int kc, int j) {
        int slot = kc & 3;
        int kbyte = kc * 64;
        int off = j * 8192 + t * 16;
        int row = off >> 6;
        int kbs = (off & 63) ^ (((row >> 1) & 3) << 4);
        gload16(gA + (size_t)row * 1024 + kbyte + kbs, smem + slot * 16384 + off);
        gload16(gB + (size_t)row * 1024 + kbyte + kbs, smem + 65536 + slot * 16384 + off);
    };

    // merged chunk: 12 ds_reads (b/a interleaved) + stage + 32 MFMA (r10 body)
    auto do_chunk = [&](int c, bool doStage) {
        const char* Ab = smem + (c & 3) * 16384;
        const char* Bb = smem + 65536 + (c & 3) * 16384;
        int kread = (g4 * 16) ^ swz;
        short8 a[8], b[4];
        #pragma unroll
        for (int ni = 0; ni < 4; ++ni) {
            b[ni] = *(const short8*)(Bb + (wc * 64 + ni * 16 + rl) * 64 + kread);
            a[ni] = *(const short8*)(Ab + (wr * 128 + ni * 16 + rl) * 64 + kread);
        }
        #pragma unroll
        for (int mi = 4; mi < 8; ++mi)
            a[mi] = *(const short8*)(Ab + (wr * 128 + mi * 16 + rl) * 64 + kread);
        if (doStage) { stage_pair(c + 3, 0); stage_pair(c + 3, 1); }
        __builtin_amdgcn_s_setprio(1);
        #pragma unroll
        for (int mi = 0; mi < 8; ++mi)
            #pragma unroll
            for (int ni = 0; ni < 4; ++ni)
                acc[mi][ni] = __builtin_amdgcn_mfma_f32_16x16x32_bf16(
                    a[mi], b[ni], acc[mi][ni], 0, 0, 0);
        __builtin_amdgcn_s_setprio(0);
    };

    // prologue: 3 chunks in flight (12 loads/thread)
    stage_pair(0, 0); stage_pair(0, 1);
    stage_pair(1, 0); stage_pair(1, 1);
    stage_pair(2, 0); stage_pair(2, 1);

    #pragma unroll 1
    for (int c = 0; c < 5; ++c) {
        asm volatile("s_waitcnt vmcnt(8)" ::: "memory");
        __builtin_amdgcn_s_barrier();
        asm volatile("" ::: "memory");
        do_chunk(c, true);
    }
    asm volatile("s_waitcnt vmcnt(8)" ::: "memory");
    __builtin_amdgcn_s_barrier();
    asm volatile("" ::: "memory");
    do_chunk(5, false);
    asm volatile("s_waitcnt vmcnt(4)" ::: "memory");
    __builtin_amdgcn_s_barrier();
    asm volatile("" ::: "memory");
    do_chunk(6, false);
    asm volatile("s_waitcnt vmcnt(0)" ::: "memory");
    __builtin_amdgcn_s_barrier();
    asm volatile("" ::: "memory");
    do_chunk(7, false);

    // epilogue: sim partial over this block's 256 d-columns (half b2); x2 for off-diagonal pair
    __syncthreads();
    float* simpart = (float*)smem;      // [256][5] stride-5 -> conflict-free
    #pragma unroll
    for (int mi = 0; mi < 8; ++mi) {
        #pragma unroll
        for (int r = 0; r < 4; ++r) {
            int Rl = wr * 128 + mi * 16 + g4 * 4 + r;
            size_t Rg = (size_t)r0 + Rl;
            float s = 0.f;
            #pragma unroll
            for (int ni = 0; ni < 4; ++ni) {
                int d = b2 * 256 + wc * 64 + ni * 16 + rl;
                s += acc[mi][ni][r] * b2f(Abf[Rg * CN + d]);
            }
            s += __shfl_xor(s, 1);
            s += __shfl_xor(s, 2);
            s += __shfl_xor(s, 4);
            s += __shfl_xor(s, 8);
            if (rl == 0) simpart[Rl * 5 + wc] = s;
        }
    }
    __syncthreads();
    if (t < 256) {
        float v = simpart[t * 5 + 0] + simpart[t * 5 + 1] +
                  simpart[t * 5 + 2] + simpart[t * 5 + 3];
        if (p == 2) v *= 2.f;
        atomicAdd(&simws[(size_t)w * MPAD2 + r0 + t], v);
    }
}

// ---------------- finish: act + conv dot + bias -> scores ----------------
__global__ void finish_kernel(const float* __restrict__ simws,
                              const float* __restrict__ conv_w,
                              const float* __restrict__ conv_b,
                              float* __restrict__ scores) {
    int q = blockIdx.x, w = blockIdx.y;
    int t = threadIdx.x;    // 128
    const float* sp = simws + (size_t)w * MPAD2 + q * HWN;
    float s = 0.f;
    for (int i = t; i < HWN; i += 128) {
        float v = sp[i];
        float a = (v >= 0.f) ? v : 0.2f * v;
        s += a * conv_w[i];
    }
    __shared__ float red[2];
    #pragma unroll
    for (int off = 32; off > 0; off >>= 1) s += __shfl_down(s, off);
    if ((t & 63) == 0) red[t >> 6] = s;
    __syncthreads();
    if (t == 0) scores[q * WAYN + w] = red[0] + red[1] + conv_b[0];
}

extern "C" void kernel_launch(void* const* d_in, const int* in_sizes, int n_in,
                              void* d_out, int out_size, void* d_ws, size_t ws_size,
                              hipStream_t stream) {
    const float* x1     = (const float*)d_in[0];
    const float* x2     = (const float*)d_in[1];
    const float* conv_w = (const float*)d_in[2];
    const float* conv_b = (const float*)d_in[3];
    float* scores = (float*)d_out;

    char* ws = (char*)d_ws;
    u16* covb    = (u16*)ws;                               // 2,621,440 B
    float* simws = (float*)(ws + 2631680);                 // 1,326,080 B
    float* covf  = (float*)(ws + 3957760);                 // 5,242,880 B
    // x2c aliases head of Abf (covmfma reads x2c before qtrans writes Abf)
    u16* x2c     = (u16*)(ws + 9200640);                   // 11,304,960 B
    u16* Abf     = (u16*)(ws + 9200640);                   // 66304*512*2 = 67,895,296 B

    wx2c_kernel<<<WAYN * CN, 64, 0, stream>>>(x2, x2c);
    init2_kernel<<<256, 256, 0, stream>>>(simws, covf, (u32*)(Abf + (size_t)MROWS * CN));
    covmfma_kernel<<<dim3(10, 1, WAYN * 3), 256, 0, stream>>>(x2c, covf);
    cov2b_kernel<<<WAYN * CN * CN / 256, 256, 0, stream>>>(covf, covb);
    qtrans_kernel<<<dim3(8, QN), 256, 0, stream>>>(x1, Abf);
    gemm256_kernel<<<8 * 33 * 15, 512, 131072, stream>>>(Abf, covb, simws);
    finish_kernel<<<dim3(QN, WAYN), 128, 0, stream>>>(simws, conv_w, conv_b, scores);
}

// Round 13
// 355.582 us; speedup vs baseline: 1.2521x; 1.0339x over previous
//
#include <hip/hip_runtime.h>
#include <hip/hip_bf16.h>

#define QN 150
#define CN 512
#define HWN 441
#define WAYN 5
#define SHOTN 5
#define NSAMP 2205           // SHOT*HW
#define MROWS (QN * HWN)     // 66150 packed rows
#define MT256 259            // ceil(66150/256)
#define MPAD2 (MT256 * 256)  // 66304
#define KP 2208              // cov K padded (32*69)
#define KPB (KP * 2)         // row bytes of x2c

typedef unsigned short u16;
typedef unsigned int u32;
typedef __attribute__((ext_vector_type(8))) short short8;
typedef __attribute__((ext_vector_type(4))) float f32x4;

__device__ __forceinline__ u16 f2b(float f) {
    return __builtin_bit_cast(u16, __float2bfloat16(f));
}
__device__ __forceinline__ float b2f(u16 h) {
    u32 u = ((u32)h) << 16;
    return __builtin_bit_cast(float, u);
}

__device__ __forceinline__ void gload16(const void* g, void* l) {
    __builtin_amdgcn_global_load_lds(
        (const __attribute__((address_space(1))) unsigned int*)g,
        (__attribute__((address_space(3))) unsigned int*)l, 16, 0, 0);
}

// pair index p in [0,10) -> (lo, hi) with lo <= hi over 4 blocks of 128
__device__ __forceinline__ void pair_decode(int p, int& lo, int& hi) {
    hi = (p >= 6) ? 3 : (p >= 3 ? 2 : (p >= 1 ? 1 : 0));
    int tri = (hi == 3) ? 6 : (hi == 2 ? 3 : (hi == 1 ? 1 : 0));
    lo = p - tri;
}

// ---------------- fused: per-(way,channel) mean + center x2 -> bf16 x2c[w][c][k] ----------------
__global__ void wx2c_kernel(const float* __restrict__ x2, u16* __restrict__ x2c) {
    int b = blockIdx.x;             // w*512 + c
    int w = b >> 9, c = b & 511;
    int lane = threadIdx.x;         // 64
    float s = 0.f;
    #pragma unroll
    for (int sh = 0; sh < SHOTN; ++sh) {
        const float* p = x2 + ((size_t)((w * SHOTN + sh) * CN + c)) * HWN;
        for (int i = lane; i < HWN; i += 64) s += p[i];
    }
    #pragma unroll
    for (int off = 32; off > 0; off >>= 1) s += __shfl_down(s, off);
    float m = __shfl(s, 0) * (1.0f / NSAMP);

    u16* dst = x2c + ((size_t)(w * CN + c)) * KP;
    #pragma unroll
    for (int sh = 0; sh < SHOTN; ++sh) {
        const float* p = x2 + ((size_t)((w * SHOTN + sh) * CN + c)) * HWN;
        for (int i = lane; i < HWN; i += 64) dst[sh * HWN + i] = f2b(p[i] - m);
    }
    if (lane < (KP - NSAMP)) dst[NSAMP + lane] = 0;
}

// ---------------- cov MFMA split-K, lower-triangle 128-blocks only ----------------
__global__ __launch_bounds__(256, 2) void covmfma_kernel(const u16* __restrict__ x2c,
                                                         float* __restrict__ covf) {
    __shared__ __align__(16) u16 As[2][128 * 32];
    __shared__ __align__(16) u16 Bs[2][128 * 32];
    int z  = blockIdx.z;
    int w  = z / 3, ksp = z - w * 3;
    int dblk, cblk;
    pair_decode(blockIdx.x, dblk, cblk);    // cblk >= dblk
    int c0 = cblk * 128;
    int d0 = dblk * 128;
    int t = threadIdx.x;
    int lane = t & 63, wid = t >> 6;
    int wr = wid >> 1, wc = wid & 1;
    int rl = lane & 15, g4 = lane >> 4;
    int swz = ((rl >> 1) & 3) << 4;
    int s0 = wid * 2048 + lane * 16;

    const char* gX = (const char*)(x2c + (size_t)w * CN * KP) + ksp * 1472; // 736 elems

    f32x4 acc[4][4];
    #pragma unroll
    for (int mi = 0; mi < 4; ++mi)
        #pragma unroll
        for (int ni = 0; ni < 4; ++ni)
            acc[mi][ni] = (f32x4){0.f, 0.f, 0.f, 0.f};

    int buf = 0;
    #pragma unroll
    for (int j = 0; j < 2; ++j) {
        int s = s0 + j * 1024;
        int row = s >> 6, kbs = (s & 63) ^ (((row >> 1) & 3) << 4);
        gload16(gX + (size_t)(c0 + row) * KPB + kbs, (char*)&As[0][0] + wid * 2048 + j * 1024);
        gload16(gX + (size_t)(d0 + row) * KPB + kbs, (char*)&Bs[0][0] + wid * 2048 + j * 1024);
    }
    __syncthreads();

    for (int ks = 0; ks < 23; ++ks) {
        if (ks < 22) {
            int koff = (ks + 1) * 64;
            #pragma unroll
            for (int j = 0; j < 2; ++j) {
                int s = s0 + j * 1024;
                int row = s >> 6, kbs = (s & 63) ^ (((row >> 1) & 3) << 4);
                gload16(gX + (size_t)(c0 + row) * KPB + koff + kbs,
                        (char*)&As[buf ^ 1][0] + wid * 2048 + j * 1024);
                gload16(gX + (size_t)(d0 + row) * KPB + koff + kbs,
                        (char*)&Bs[buf ^ 1][0] + wid * 2048 + j * 1024);
            }
        }
        const char* Ab = (const char*)&As[buf][0];
        const char* Bb = (const char*)&Bs[buf][0];
        int kread = (g4 * 16) ^ swz;
        short8 a[4], b[4];
        #pragma unroll
        for (int mi = 0; mi < 4; ++mi)
            a[mi] = *(const short8*)(Ab + (wr * 64 + mi * 16 + rl) * 64 + kread);
        #pragma unroll
        for (int ni = 0; ni < 4; ++ni)
            b[ni] = *(const short8*)(Bb + (wc * 64 + ni * 16 + rl) * 64 + kread);
        #pragma unroll
        for (int mi = 0; mi < 4; ++mi)
            #pragma unroll
            for (int ni = 0; ni < 4; ++ni)
                acc[mi][ni] = __builtin_amdgcn_mfma_f32_16x16x32_bf16(
                    a[mi], b[ni], acc[mi][ni], 0, 0, 0);
        __syncthreads();
        buf ^= 1;
    }

    const float inv = 1.0f / (NSAMP - 1);
    #pragma unroll
    for (int mi = 0; mi < 4; ++mi)
        #pragma unroll
        for (int r = 0; r < 4; ++r) {
            int c = c0 + wr * 64 + mi * 16 + g4 * 4 + r;
            #pragma unroll
            for (int ni = 0; ni < 4; ++ni) {
                int d = d0 + wc * 64 + ni * 16 + rl;
                atomicAdd(&covf[((size_t)w * CN + c) * CN + d], acc[mi][ni][r] * inv);
            }
        }
}

// ---------------- covf (lower-triangle blocks) -> covb bf16, symmetrized full ----------------
__global__ void cov2b_kernel(const float* __restrict__ covf, u16* __restrict__ covb) {
    int i = blockIdx.x * 256 + threadIdx.x;        // w*CN*CN + c*CN + d
    int w = i >> 18;
    int cd = i & ((1 << 18) - 1);
    int c = cd >> 9, d = cd & 511;
    int cb = c >> 7, db = d >> 7;
    size_t src;
    if (cb >= db) src = ((size_t)w << 18) + ((size_t)c << 9) + d;
    else          src = ((size_t)w << 18) + ((size_t)d << 9) + c;   // mirror from lower block
    covb[i] = f2b(covf[src]);
}

// ---------------- transpose+center x1 -> Abf[(q*441+i)][c] bf16 (packed rows) ----------------
__global__ __launch_bounds__(256) void qtrans_kernel(const float* __restrict__ x1,
                                                     u16* __restrict__ Abf) {
    __shared__ u16 S[512][72];
    __shared__ float qm[64];
    int c0 = blockIdx.x * 64;
    int q  = blockIdx.y;
    int t = threadIdx.x;
    int lane = t & 63, cq = t >> 6;

    for (int cc = cq; cc < 64; cc += 4) {
        int c = c0 + cc;
        const float* p = x1 + ((size_t)q * CN + c) * HWN;
        float s = 0.f;
        for (int ic = 0; ic < 8; ++ic) {
            int i = ic * 64 + lane;
            float v = (i < HWN) ? p[i] : 0.f;
            s += v;
            S[i][cc] = f2b(v);
        }
        #pragma unroll
        for (int off = 32; off > 0; off >>= 1) s += __shfl_down(s, off);
        if (lane == 0) qm[cc] = s * (1.0f / HWN);
    }
    __syncthreads();

    int coct = t & 7;
    for (int p = 0; p < 16; ++p) {
        int il = p * 32 + (t >> 3);
        if (il >= HWN) continue;
        short8 v = *(const short8*)(&S[il][coct * 8]);
        short8 o;
        #pragma unroll
        for (int j = 0; j < 8; ++j) {
            float f = b2f((u16)v[j]) - qm[coct * 8 + j];
            o[j] = (short)f2b(f);
        }
        *(short8*)(Abf + ((size_t)(q * HWN + il)) * CN + c0 + coct * 8) = o;
    }
}

// ---------------- init: zero simws + covf + Abf pad rows ----------------
__global__ void init2_kernel(float* __restrict__ simws, float* __restrict__ covf,
                             u32* __restrict__ AbfPad32) {
    int tid = blockIdx.x * blockDim.x + threadIdx.x;
    int stride = gridDim.x * blockDim.x;
    int nsim = WAYN * MPAD2;
    for (int i = tid; i < nsim; i += stride) simws[i] = 0.f;
    int ncov = WAYN * CN * CN;
    for (int i = tid; i < ncov; i += stride) covf[i] = 0.f;
    int npadw = (MPAD2 - MROWS) * CN / 2;
    for (int i = tid; i < npadw; i += stride) AbfPad32[i] = 0;
}

// ---------------- main: 256x256 tile, m201-faithful 8-phase (4 phases / K=64 tile) ----------------
// 512 thr = 8 waves (2M x 4N), wave out 128x64. K=512 -> 8 K-tiles of 64.
// LDS: 2 slots x (A 32KB + B 32KB) = 128 KiB; within slot: [ksub(2)][256 rows][64B], XOR-swizzled.
// Phase = {ds_read subtile; stage half-tile; barrier; lgkmcnt(0); setprio 16-MFMA; barrier}.
// Staging of kt+1 happens in p0/p1 of kt; vmcnt(0) at p3 (loads >=2 phases old) before its
// trailing barrier, so kt+1's data is published before any wave reads it at kt+1 p0.
__global__ __launch_bounds__(512, 2) void gemm8p_kernel(const u16* __restrict__ Abf,
                                                        const u16* __restrict__ covb,
                                                        float* __restrict__ simws) {
    extern __shared__ char smem[];

    int x = blockIdx.x & 7;
    int l = blockIdx.x >> 3;
    int m = x * 33 + l / 10;
    if (m >= MT256) return;
    int nw = l - (l / 10) * 10;
    int w  = nw % 5;
    int n0 = (nw / 5) * 256;
    int r0 = m * 256;

    int t = threadIdx.x;
    int lane = t & 63, wid = t >> 6;
    int wr = wid >> 2, wc = wid & 3;        // 2M x 4N waves
    int rl = lane & 15, g4 = lane >> 4;
    int swz = ((rl >> 1) & 3) << 4;
    int kread = (g4 * 16) ^ swz;

    const char* gA = (const char*)(Abf + (size_t)r0 * CN);               // row stride 1024 B
    const char* gB = (const char*)(covb + ((size_t)w * CN + n0) * CN);   // row stride 1024 B

    f32x4 acc[8][4];
    #pragma unroll
    for (int mi = 0; mi < 8; ++mi)
        #pragma unroll
        for (int ni = 0; ni < 4; ++ni)
            acc[mi][ni] = (f32x4){0.f, 0.f, 0.f, 0.f};

    short8 a[8], b0[4], b1[4];

    // stage half-tile h (128 rows) of op (0=A,1=B) for K-tile kt into slot kt&1: 2 gloads
    auto stage_half = [&](int kt, int op, int h) {
        char* base = smem + (kt & 1) * 65536 + op * 32768;
        const char* g = op ? gB : gA;
        #pragma unroll
        for (int j = 0; j < 2; ++j) {       // ksub
            int off = t * 16;
            int row = off >> 6;             // 0..127 local
            int kbs = (off & 63) ^ (((row >> 1) & 3) << 4);
            gload16(g + (size_t)(h * 128 + row) * 1024 + kt * 128 + j * 64 + kbs,
                    base + j * 16384 + h * 8192 + off);
        }
    };

    auto rdA = [&](int kt, int row, int ks) -> short8 {
        return *(const short8*)(smem + (kt & 1) * 65536 + ks * 16384 + row * 64 + kread);
    };
    auto rdB = [&](int kt, int row, int ks) -> short8 {
        return *(const short8*)(smem + (kt & 1) * 65536 + 32768 + ks * 16384 + row * 64 + kread);
    };

    #define MIDSYNC() do { \
        asm volatile("" ::: "memory"); \
        __builtin_amdgcn_s_barrier(); \
        asm volatile("s_waitcnt lgkmcnt(0)" ::: "memory"); \
        __builtin_amdgcn_sched_barrier(0); \
    } while (0)
    #define ENDSYNC() do { \
        asm volatile("" ::: "memory"); \
        __builtin_amdgcn_s_barrier(); \
        asm volatile("" ::: "memory"); \
    } while (0)
    #define MFMA_Q(MIB, NIB, BV) do { \
        __builtin_amdgcn_s_setprio(1); \
        _Pragma("unroll") \
        for (int mi = 0; mi < 4; ++mi) \
            _Pragma("unroll") \
            for (int ni = 0; ni < 2; ++ni) \
                _Pragma("unroll") \
                for (int ks = 0; ks < 2; ++ks) \
                    acc[(MIB) + mi][(NIB) + ni] = __builtin_amdgcn_mfma_f32_16x16x32_bf16( \
                        a[mi * 2 + ks], BV[ni * 2 + ks], acc[(MIB) + mi][(NIB) + ni], 0, 0, 0); \
        __builtin_amdgcn_s_setprio(0); \
    } while (0)

    // prologue: stage K-tile 0 fully, publish
    stage_half(0, 0, 0); stage_half(0, 1, 0);
    stage_half(0, 0, 1); stage_half(0, 1, 1);
    asm volatile("s_waitcnt vmcnt(0)" ::: "memory");
    __builtin_amdgcn_s_barrier();
    asm volatile("" ::: "memory");

    auto ktile = [&](int kt, bool doStage) {
        // ---- p0: read a(lo half: mi 0-3) + b0 (ni 0-1); stage kt+1 h0 ----
        #pragma unroll
        for (int mi = 0; mi < 4; ++mi)
            #pragma unroll
            for (int ks = 0; ks < 2; ++ks)
                a[mi * 2 + ks] = rdA(kt, wr * 128 + mi * 16 + rl, ks);
        #pragma unroll
        for (int ni = 0; ni < 2; ++ni)
            #pragma unroll
            for (int ks = 0; ks < 2; ++ks)
                b0[ni * 2 + ks] = rdB(kt, wc * 64 + ni * 16 + rl, ks);
        if (doStage) { stage_half(kt + 1, 0, 0); stage_half(kt + 1, 1, 0); }
        MIDSYNC();
        MFMA_Q(0, 0, b0);
        ENDSYNC();
        // ---- p1: read b1 (ni 2-3); stage kt+1 h1 ----
        #pragma unroll
        for (int ni = 0; ni < 2; ++ni)
            #pragma unroll
            for (int ks = 0; ks < 2; ++ks)
                b1[ni * 2 + ks] = rdB(kt, wc * 64 + 32 + ni * 16 + rl, ks);
        if (doStage) { stage_half(kt + 1, 0, 1); stage_half(kt + 1, 1, 1); }
        MIDSYNC();
        MFMA_Q(0, 2, b1);
        ENDSYNC();
        // ---- p2: read a(hi half: mi 4-7) ----
        #pragma unroll
        for (int mi = 0; mi < 4; ++mi)
            #pragma unroll
            for (int ks = 0; ks < 2; ++ks)
                a[mi * 2 + ks] = rdA(kt, wr * 128 + 64 + mi * 16 + rl, ks);
        MIDSYNC();
        MFMA_Q(4, 2, b1);
        ENDSYNC();
        // ---- p3: no reads; drain stages of kt+1 before publishing ----
        MIDSYNC();
        MFMA_Q(4, 0, b0);
        asm volatile("s_waitcnt vmcnt(0)" ::: "memory");
        ENDSYNC();
    };

    #pragma unroll 1
    for (int kt = 0; kt < 7; ++kt) ktile(kt, true);
    ktile(7, false);

    #undef MIDSYNC
    #undef ENDSYNC
    #undef MFMA_Q

    // epilogue: partial sim over this block's 256 d-columns
    __syncthreads();
    float* simpart = (float*)smem;      // [256][5] stride-5 -> conflict-free
    #pragma unroll
    for (int mi = 0; mi < 8; ++mi) {
        #pragma unroll
        for (int r = 0; r < 4; ++r) {
            int Rl = wr * 128 + mi * 16 + g4 * 4 + r;
            size_t Rg = (size_t)r0 + Rl;
            float s = 0.f;
            #pragma unroll
            for (int ni = 0; ni < 4; ++ni) {
                int d = n0 + wc * 64 + ni * 16 + rl;
                s += acc[mi][ni][r] * b2f(Abf[Rg * CN + d]);
            }
            s += __shfl_xor(s, 1);
            s += __shfl_xor(s, 2);
            s += __shfl_xor(s, 4);
            s += __shfl_xor(s, 8);
            if (rl == 0) simpart[Rl * 5 + wc] = s;
        }
    }
    __syncthreads();
    if (t < 256) {
        float v = simpart[t * 5 + 0] + simpart[t * 5 + 1] +
                  simpart[t * 5 + 2] + simpart[t * 5 + 3];
        atomicAdd(&simws[(size_t)w * MPAD2 + r0 + t], v);
    }
}

// ---------------- finish: act + conv dot + bias -> scores ----------------
__global__ void finish_kernel(const float* __restrict__ simws,
                              const float* __restrict__ conv_w,
                              const float* __restrict__ conv_b,
                              float* __restrict__ scores) {
    int q = blockIdx.x, w = blockIdx.y;
    int t = threadIdx.x;    // 128
    const float* sp = simws + (size_t)w * MPAD2 + q * HWN;
    float s = 0.f;
    for (int i = t; i < HWN; i += 128) {
        float v = sp[i];
        float a = (v >= 0.f) ? v : 0.2f * v;
        s += a * conv_w[i];
    }
    __shared__ float red[2];
    #pragma unroll
    for (int off = 32; off > 0; off >>= 1) s += __shfl_down(s, off);
    if ((t & 63) == 0) red[t >> 6] = s;
    __syncthreads();
    if (t == 0) scores[q * WAYN + w] = red[0] + red[1] + conv_b[0];
}

extern "C" void kernel_launch(void* const* d_in, const int* in_sizes, int n_in,
                              void* d_out, int out_size, void* d_ws, size_t ws_size,
                              hipStream_t stream) {
    const float* x1     = (const float*)d_in[0];
    const float* x2     = (const float*)d_in[1];
    const float* conv_w = (const float*)d_in[2];
    const float* conv_b = (const float*)d_in[3];
    float* scores = (float*)d_out;

    char* ws = (char*)d_ws;
    u16* covb    = (u16*)ws;                               // 2,621,440 B
    float* simws = (float*)(ws + 2631680);                 // 1,326,080 B
    float* covf  = (float*)(ws + 3957760);                 // 5,242,880 B
    // x2c aliases head of Abf (covmfma reads x2c before qtrans writes Abf)
    u16* x2c     = (u16*)(ws + 9200640);                   // 11,304,960 B
    u16* Abf     = (u16*)(ws + 9200640);                   // 66304*512*2 = 67,895,296 B

    wx2c_kernel<<<WAYN * CN, 64, 0, stream>>>(x2, x2c);
    init2_kernel<<<256, 256, 0, stream>>>(simws, covf, (u32*)(Abf + (size_t)MROWS * CN));
    covmfma_kernel<<<dim3(10, 1, WAYN * 3), 256, 0, stream>>>(x2c, covf);
    cov2b_kernel<<<WAYN * CN * CN / 256, 256, 0, stream>>>(covf, covb);
    qtrans_kernel<<<dim3(8, QN), 256, 0, stream>>>(x1, Abf);
    gemm8p_kernel<<<8 * 330, 512, 131072, stream>>>(Abf, covb, simws);
    finish_kernel<<<dim3(QN, WAYN), 128, 0, stream>>>(simws, conv_w, conv_b, scores);
}

// Round 14
// 322.281 us; speedup vs baseline: 1.3815x; 1.1033x over previous
//
#include <hip/hip_runtime.h>
#include <hip/hip_bf16.h>

#define QN 150
#define CN 512
#define HWN 441
#define WAYN 5
#define SHOTN 5
#define NSAMP 2205           // SHOT*HW
#define MROWS (QN * HWN)     // 66150 packed rows
#define MT128 517            // ceil(66150/128)
#define MPAD2 66304          // init2 zero coverage (>= MT128*128 = 66176)
#define KP 2208              // cov K padded (32*69)
#define KPB (KP * 2)         // row bytes of x2c

typedef unsigned short u16;
typedef unsigned int u32;
typedef __attribute__((ext_vector_type(8))) short short8;
typedef __attribute__((ext_vector_type(4))) float f32x4;

__device__ __forceinline__ u16 f2b(float f) {
    return __builtin_bit_cast(u16, __float2bfloat16(f));
}
__device__ __forceinline__ float b2f(u16 h) {
    u32 u = ((u32)h) << 16;
    return __builtin_bit_cast(float, u);
}

__device__ __forceinline__ void gload16(const void* g, void* l) {
    __builtin_amdgcn_global_load_lds(
        (const __attribute__((address_space(1))) unsigned int*)g,
        (__attribute__((address_space(3))) unsigned int*)l, 16, 0, 0);
}

// pair index p in [0,10) -> (lo, hi) with lo <= hi over 4 blocks of 128
__device__ __forceinline__ void pair_decode(int p, int& lo, int& hi) {
    hi = (p >= 6) ? 3 : (p >= 3 ? 2 : (p >= 1 ? 1 : 0));
    int tri = (hi == 3) ? 6 : (hi == 2 ? 3 : (hi == 1 ? 1 : 0));
    lo = p - tri;
}

// ---------------- fused: per-(way,channel) mean + center x2 -> bf16 x2c[w][c][k] ----------------
__global__ void wx2c_kernel(const float* __restrict__ x2, u16* __restrict__ x2c) {
    int b = blockIdx.x;             // w*512 + c
    int w = b >> 9, c = b & 511;
    int lane = threadIdx.x;         // 64
    float s = 0.f;
    #pragma unroll
    for (int sh = 0; sh < SHOTN; ++sh) {
        const float* p = x2 + ((size_t)((w * SHOTN + sh) * CN + c)) * HWN;
        for (int i = lane; i < HWN; i += 64) s += p[i];
    }
    #pragma unroll
    for (int off = 32; off > 0; off >>= 1) s += __shfl_down(s, off);
    float m = __shfl(s, 0) * (1.0f / NSAMP);

    u16* dst = x2c + ((size_t)(w * CN + c)) * KP;
    #pragma unroll
    for (int sh = 0; sh < SHOTN; ++sh) {
        const float* p = x2 + ((size_t)((w * SHOTN + sh) * CN + c)) * HWN;
        for (int i = lane; i < HWN; i += 64) dst[sh * HWN + i] = f2b(p[i] - m);
    }
    if (lane < (KP - NSAMP)) dst[NSAMP + lane] = 0;
}

// ---------------- cov MFMA split-K, lower-triangle 128-blocks only ----------------
__global__ __launch_bounds__(256, 2) void covmfma_kernel(const u16* __restrict__ x2c,
                                                         float* __restrict__ covf) {
    __shared__ __align__(16) u16 As[2][128 * 32];
    __shared__ __align__(16) u16 Bs[2][128 * 32];
    int z  = blockIdx.z;
    int w  = z / 3, ksp = z - w * 3;
    int dblk, cblk;
    pair_decode(blockIdx.x, dblk, cblk);    // cblk >= dblk
    int c0 = cblk * 128;
    int d0 = dblk * 128;
    int t = threadIdx.x;
    int lane = t & 63, wid = t >> 6;
    int wr = wid >> 1, wc = wid & 1;
    int rl = lane & 15, g4 = lane >> 4;
    int swz = ((rl >> 1) & 3) << 4;
    int s0 = wid * 2048 + lane * 16;

    const char* gX = (const char*)(x2c + (size_t)w * CN * KP) + ksp * 1472; // 736 elems

    f32x4 acc[4][4];
    #pragma unroll
    for (int mi = 0; mi < 4; ++mi)
        #pragma unroll
        for (int ni = 0; ni < 4; ++ni)
            acc[mi][ni] = (f32x4){0.f, 0.f, 0.f, 0.f};

    int buf = 0;
    #pragma unroll
    for (int j = 0; j < 2; ++j) {
        int s = s0 + j * 1024;
        int row = s >> 6, kbs = (s & 63) ^ (((row >> 1) & 3) << 4);
        gload16(gX + (size_t)(c0 + row) * KPB + kbs, (char*)&As[0][0] + wid * 2048 + j * 1024);
        gload16(gX + (size_t)(d0 + row) * KPB + kbs, (char*)&Bs[0][0] + wid * 2048 + j * 1024);
    }
    __syncthreads();

    for (int ks = 0; ks < 23; ++ks) {
        if (ks < 22) {
            int koff = (ks + 1) * 64;
            #pragma unroll
            for (int j = 0; j < 2; ++j) {
                int s = s0 + j * 1024;
                int row = s >> 6, kbs = (s & 63) ^ (((row >> 1) & 3) << 4);
                gload16(gX + (size_t)(c0 + row) * KPB + koff + kbs,
                        (char*)&As[buf ^ 1][0] + wid * 2048 + j * 1024);
                gload16(gX + (size_t)(d0 + row) * KPB + koff + kbs,
                        (char*)&Bs[buf ^ 1][0] + wid * 2048 + j * 1024);
            }
        }
        const char* Ab = (const char*)&As[buf][0];
        const char* Bb = (const char*)&Bs[buf][0];
        int kread = (g4 * 16) ^ swz;
        short8 a[4], b[4];
        #pragma unroll
        for (int mi = 0; mi < 4; ++mi)
            a[mi] = *(const short8*)(Ab + (wr * 64 + mi * 16 + rl) * 64 + kread);
        #pragma unroll
        for (int ni = 0; ni < 4; ++ni)
            b[ni] = *(const short8*)(Bb + (wc * 64 + ni * 16 + rl) * 64 + kread);
        #pragma unroll
        for (int mi = 0; mi < 4; ++mi)
            #pragma unroll
            for (int ni = 0; ni < 4; ++ni)
                acc[mi][ni] = __builtin_amdgcn_mfma_f32_16x16x32_bf16(
                    a[mi], b[ni], acc[mi][ni], 0, 0, 0);
        __syncthreads();
        buf ^= 1;
    }

    const float inv = 1.0f / (NSAMP - 1);
    #pragma unroll
    for (int mi = 0; mi < 4; ++mi)
        #pragma unroll
        for (int r = 0; r < 4; ++r) {
            int c = c0 + wr * 64 + mi * 16 + g4 * 4 + r;
            #pragma unroll
            for (int ni = 0; ni < 4; ++ni) {
                int d = d0 + wc * 64 + ni * 16 + rl;
                atomicAdd(&covf[((size_t)w * CN + c) * CN + d], acc[mi][ni][r] * inv);
            }
        }
}

// ---------------- covf (lower-triangle blocks) -> covb bf16, symmetrized full ----------------
__global__ void cov2b_kernel(const float* __restrict__ covf, u16* __restrict__ covb) {
    int i = blockIdx.x * 256 + threadIdx.x;        // w*CN*CN + c*CN + d
    int w = i >> 18;
    int cd = i & ((1 << 18) - 1);
    int c = cd >> 9, d = cd & 511;
    int cb = c >> 7, db = d >> 7;
    size_t src;
    if (cb >= db) src = ((size_t)w << 18) + ((size_t)c << 9) + d;
    else          src = ((size_t)w << 18) + ((size_t)d << 9) + c;   // mirror from lower block
    covb[i] = f2b(covf[src]);
}

// ---------------- transpose+center x1 -> Abf[(q*441+i)][c] bf16 (packed rows) ----------------
__global__ __launch_bounds__(256) void qtrans_kernel(const float* __restrict__ x1,
                                                     u16* __restrict__ Abf) {
    __shared__ u16 S[512][72];
    __shared__ float qm[64];
    int c0 = blockIdx.x * 64;
    int q  = blockIdx.y;
    int t = threadIdx.x;
    int lane = t & 63, cq = t >> 6;

    for (int cc = cq; cc < 64; cc += 4) {
        int c = c0 + cc;
        const float* p = x1 + ((size_t)q * CN + c) * HWN;
        float s = 0.f;
        for (int ic = 0; ic < 8; ++ic) {
            int i = ic * 64 + lane;
            float v = (i < HWN) ? p[i] : 0.f;
            s += v;
            S[i][cc] = f2b(v);
        }
        #pragma unroll
        for (int off = 32; off > 0; off >>= 1) s += __shfl_down(s, off);
        if (lane == 0) qm[cc] = s * (1.0f / HWN);
    }
    __syncthreads();

    int coct = t & 7;
    for (int p = 0; p < 16; ++p) {
        int il = p * 32 + (t >> 3);
        if (il >= HWN) continue;
        short8 v = *(const short8*)(&S[il][coct * 8]);
        short8 o;
        #pragma unroll
        for (int j = 0; j < 8; ++j) {
            float f = b2f((u16)v[j]) - qm[coct * 8 + j];
            o[j] = (short)f2b(f);
        }
        *(short8*)(Abf + ((size_t)(q * HWN + il)) * CN + c0 + coct * 8) = o;
    }
}

// ---------------- init: zero simws + covf + Abf pad rows ----------------
__global__ void init2_kernel(float* __restrict__ simws, float* __restrict__ covf,
                             u32* __restrict__ AbfPad32) {
    int tid = blockIdx.x * blockDim.x + threadIdx.x;
    int stride = gridDim.x * blockDim.x;
    int nsim = WAYN * MPAD2;
    for (int i = tid; i < nsim; i += stride) simws[i] = 0.f;
    int ncov = WAYN * CN * CN;
    for (int i = tid; i < ncov; i += stride) covf[i] = 0.f;
    int npadw = (MPAD2 - MROWS) * CN / 2;
    for (int i = tid; i < npadw; i += stride) AbfPad32[i] = 0;
}

// ---------------- main: m97-style 128x128 tile, 4 waves, ring-2, 3 blocks/CU ----------------
// Grid 8*65*20: XCD group (bid&7) x 65 m-tiles x (4 n-tiles x 5 w innermost -> 20 consecutive
// blocks share one A m-tile on one XCD's L2). Per block: K=512 = 16 chunks of 32.
// LDS 33.5 KB static; VGPR target <=170 -> 3 blocks/CU => m114 cross-block overlap fills
// the stage/vmcnt/barrier gaps that killed the 1-block/CU 256^2 variants (m233 regime).
__global__ __launch_bounds__(256, 3) void gemm128_kernel(const u16* __restrict__ Abf,
                                                         const u16* __restrict__ covb,
                                                         float* __restrict__ simws) {
    __shared__ __align__(16) u16 As[2][128 * 32];
    __shared__ __align__(16) u16 Bs[2][128 * 32];
    __shared__ float simpart[128 * 3];

    int x = blockIdx.x & 7;
    int l = blockIdx.x >> 3;
    int g = l / 20;
    int m = x * 65 + g;
    if (m >= MT128) return;
    int inner = l - g * 20;
    int w  = inner % 5;
    int n0 = (inner / 5) * 128;
    int r0 = m * 128;

    int t = threadIdx.x;
    int lane = t & 63, wid = t >> 6;
    int wr = wid >> 1, wc = wid & 1;        // 2M x 2N waves, wave tile 64x64
    int rl = lane & 15, g4 = lane >> 4;
    int swz = ((rl >> 1) & 3) << 4;
    int kread = (g4 * 16) ^ swz;

    const char* gA = (const char*)(Abf + (size_t)r0 * CN);               // row stride 1024 B
    const char* gB = (const char*)(covb + ((size_t)w * CN + n0) * CN);   // row stride 1024 B

    f32x4 acc[4][4];
    #pragma unroll
    for (int mi = 0; mi < 4; ++mi)
        #pragma unroll
        for (int ni = 0; ni < 4; ++ni)
            acc[mi][ni] = (f32x4){0.f, 0.f, 0.f, 0.f};

    // stage chunk kc into slot kc&1: 2 A + 2 B gload16 per thread (8 KB each op)
    auto stage_chunk = [&](int kc) {
        int slot = kc & 1;
        int kbyte = kc * 64;
        #pragma unroll
        for (int j = 0; j < 2; ++j) {
            int off = j * 4096 + t * 16;
            int row = off >> 6;
            int kbs = (off & 63) ^ (((row >> 1) & 3) << 4);
            gload16(gA + (size_t)row * 1024 + kbyte + kbs, (char*)&As[slot][0] + off);
            gload16(gB + (size_t)row * 1024 + kbyte + kbs, (char*)&Bs[slot][0] + off);
        }
    };

    // merged chunk body (r10-proven): 8 ds_reads (b/a interleaved) then 16 MFMA
    auto do_chunk = [&](int c) {
        const char* Ab = (const char*)&As[c & 1][0];
        const char* Bb = (const char*)&Bs[c & 1][0];
        short8 a[4], b[4];
        #pragma unroll
        for (int ni = 0; ni < 4; ++ni) {
            b[ni] = *(const short8*)(Bb + (wc * 64 + ni * 16 + rl) * 64 + kread);
            a[ni] = *(const short8*)(Ab + (wr * 64 + ni * 16 + rl) * 64 + kread);
        }
        __builtin_amdgcn_s_setprio(1);
        #pragma unroll
        for (int mi = 0; mi < 4; ++mi)
            #pragma unroll
            for (int ni = 0; ni < 4; ++ni)
                acc[mi][ni] = __builtin_amdgcn_mfma_f32_16x16x32_bf16(
                    a[mi], b[ni], acc[mi][ni], 0, 0, 0);
        __builtin_amdgcn_s_setprio(0);
        // reads retired before MFMAs issued -> next top barrier closes this slot
    };

    stage_chunk(0);

    #pragma unroll 1
    for (int c = 0; c < 16; ++c) {
        asm volatile("s_waitcnt vmcnt(0)" ::: "memory");   // chunk-c loads landed (issued 1 chunk ago)
        __builtin_amdgcn_s_barrier();
        asm volatile("" ::: "memory");
        if (c < 15) stage_chunk(c + 1);                    // depth-1 prefetch into other slot
        do_chunk(c);
    }

    // epilogue: partial sim over this block's 128 d-columns
    __syncthreads();
    #pragma unroll
    for (int mi = 0; mi < 4; ++mi) {
        #pragma unroll
        for (int r = 0; r < 4; ++r) {
            int Rl = wr * 64 + mi * 16 + g4 * 4 + r;
            size_t Rg = (size_t)r0 + Rl;
            float s = 0.f;
            #pragma unroll
            for (int ni = 0; ni < 4; ++ni) {
                int d = n0 + wc * 64 + ni * 16 + rl;
                s += acc[mi][ni][r] * b2f(Abf[Rg * CN + d]);
            }
            s += __shfl_xor(s, 1);
            s += __shfl_xor(s, 2);
            s += __shfl_xor(s, 4);
            s += __shfl_xor(s, 8);
            if (rl == 0) simpart[Rl * 3 + wc] = s;
        }
    }
    __syncthreads();
    if (t < 128) {
        float v = simpart[t * 3 + 0] + simpart[t * 3 + 1];
        atomicAdd(&simws[(size_t)w * MPAD2 + r0 + t], v);
    }
}

// ---------------- finish: act + conv dot + bias -> scores ----------------
__global__ void finish_kernel(const float* __restrict__ simws,
                              const float* __restrict__ conv_w,
                              const float* __restrict__ conv_b,
                              float* __restrict__ scores) {
    int q = blockIdx.x, w = blockIdx.y;
    int t = threadIdx.x;    // 128
    const float* sp = simws + (size_t)w * MPAD2 + q * HWN;
    float s = 0.f;
    for (int i = t; i < HWN; i += 128) {
        float v = sp[i];
        float a = (v >= 0.f) ? v : 0.2f * v;
        s += a * conv_w[i];
    }
    __shared__ float red[2];
    #pragma unroll
    for (int off = 32; off > 0; off >>= 1) s += __shfl_down(s, off);
    if ((t & 63) == 0) red[t >> 6] = s;
    __syncthreads();
    if (t == 0) scores[q * WAYN + w] = red[0] + red[1] + conv_b[0];
}

extern "C" void kernel_launch(void* const* d_in, const int* in_sizes, int n_in,
                              void* d_out, int out_size, void* d_ws, size_t ws_size,
                              hipStream_t stream) {
    const float* x1     = (const float*)d_in[0];
    const float* x2     = (const float*)d_in[1];
    const float* conv_w = (const float*)d_in[2];
    const float* conv_b = (const float*)d_in[3];
    float* scores = (float*)d_out;

    char* ws = (char*)d_ws;
    u16* covb    = (u16*)ws;                               // 2,621,440 B
    float* simws = (float*)(ws + 2631680);                 // 1,326,080 B
    float* covf  = (float*)(ws + 3957760);                 // 5,242,880 B
    // x2c aliases head of Abf (covmfma reads x2c before qtrans writes Abf)
    u16* x2c     = (u16*)(ws + 9200640);                   // 11,304,960 B
    u16* Abf     = (u16*)(ws + 9200640);                   // 66304*512*2 = 67,895,296 B

    wx2c_kernel<<<WAYN * CN, 64, 0, stream>>>(x2, x2c);
    init2_kernel<<<256, 256, 0, stream>>>(simws, covf, (u32*)(Abf + (size_t)MROWS * CN));
    covmfma_kernel<<<dim3(10, 1, WAYN * 3), 256, 0, stream>>>(x2c, covf);
    cov2b_kernel<<<WAYN * CN * CN / 256, 256, 0, stream>>>(covf, covb);
    qtrans_kernel<<<dim3(8, QN), 256, 0, stream>>>(x1, Abf);
    gemm128_kernel<<<8 * 65 * 20, 256, 0, stream>>>(Abf, covb, simws);
    finish_kernel<<<dim3(QN, WAYN), 128, 0, stream>>>(simws, conv_w, conv_b, scores);
}

// Round 15
// 305.339 us; speedup vs baseline: 1.4582x; 1.0555x over previous
//
#include <hip/hip_runtime.h>
#include <hip/hip_bf16.h>

#define QN 150
#define CN 512
#define HWN 441
#define WAYN 5
#define SHOTN 5
#define NSAMP 2205           // SHOT*HW
#define MROWS (QN * HWN)     // 66150 packed rows
#define MT128 517            // ceil(66150/128)
#define MPAD2 66304          // init2 zero coverage (>= MT128*128 = 66176)
#define KP 2208              // cov K padded (32*69)
#define KPB (KP * 2)         // row bytes of x2c

typedef unsigned short u16;
typedef unsigned int u32;
typedef __attribute__((ext_vector_type(8))) short short8;
typedef __attribute__((ext_vector_type(4))) float f32x4;

__device__ __forceinline__ u16 f2b(float f) {
    return __builtin_bit_cast(u16, __float2bfloat16(f));
}
__device__ __forceinline__ float b2f(u16 h) {
    u32 u = ((u32)h) << 16;
    return __builtin_bit_cast(float, u);
}

__device__ __forceinline__ void gload16(const void* g, void* l) {
    __builtin_amdgcn_global_load_lds(
        (const __attribute__((address_space(1))) unsigned int*)g,
        (__attribute__((address_space(3))) unsigned int*)l, 16, 0, 0);
}

// pair index p in [0,10) -> (lo, hi) with lo <= hi over 4 blocks of 128
__device__ __forceinline__ void pair_decode(int p, int& lo, int& hi) {
    hi = (p >= 6) ? 3 : (p >= 3 ? 2 : (p >= 1 ? 1 : 0));
    int tri = (hi == 3) ? 6 : (hi == 2 ? 3 : (hi == 1 ? 1 : 0));
    lo = p - tri;
}

// ---------------- fused: per-(way,channel) mean + center x2 -> bf16 x2c[w][c][k] ----------------
__global__ void wx2c_kernel(const float* __restrict__ x2, u16* __restrict__ x2c) {
    int b = blockIdx.x;             // w*512 + c
    int w = b >> 9, c = b & 511;
    int lane = threadIdx.x;         // 64
    float s = 0.f;
    #pragma unroll
    for (int sh = 0; sh < SHOTN; ++sh) {
        const float* p = x2 + ((size_t)((w * SHOTN + sh) * CN + c)) * HWN;
        for (int i = lane; i < HWN; i += 64) s += p[i];
    }
    #pragma unroll
    for (int off = 32; off > 0; off >>= 1) s += __shfl_down(s, off);
    float m = __shfl(s, 0) * (1.0f / NSAMP);

    u16* dst = x2c + ((size_t)(w * CN + c)) * KP;
    #pragma unroll
    for (int sh = 0; sh < SHOTN; ++sh) {
        const float* p = x2 + ((size_t)((w * SHOTN + sh) * CN + c)) * HWN;
        for (int i = lane; i < HWN; i += 64) dst[sh * HWN + i] = f2b(p[i] - m);
    }
    if (lane < (KP - NSAMP)) dst[NSAMP + lane] = 0;
}

// ---------------- cov MFMA split-K, lower-triangle 128-blocks only ----------------
__global__ __launch_bounds__(256, 2) void covmfma_kernel(const u16* __restrict__ x2c,
                                                         float* __restrict__ covf) {
    __shared__ __align__(16) u16 As[2][128 * 32];
    __shared__ __align__(16) u16 Bs[2][128 * 32];
    int z  = blockIdx.z;
    int w  = z / 3, ksp = z - w * 3;
    int dblk, cblk;
    pair_decode(blockIdx.x, dblk, cblk);    // cblk >= dblk
    int c0 = cblk * 128;
    int d0 = dblk * 128;
    int t = threadIdx.x;
    int lane = t & 63, wid = t >> 6;
    int wr = wid >> 1, wc = wid & 1;
    int rl = lane & 15, g4 = lane >> 4;
    int swz = ((rl >> 1) & 3) << 4;
    int s0 = wid * 2048 + lane * 16;

    const char* gX = (const char*)(x2c + (size_t)w * CN * KP) + ksp * 1472; // 736 elems

    f32x4 acc[4][4];
    #pragma unroll
    for (int mi = 0; mi < 4; ++mi)
        #pragma unroll
        for (int ni = 0; ni < 4; ++ni)
            acc[mi][ni] = (f32x4){0.f, 0.f, 0.f, 0.f};

    int buf = 0;
    #pragma unroll
    for (int j = 0; j < 2; ++j) {
        int s = s0 + j * 1024;
        int row = s >> 6, kbs = (s & 63) ^ (((row >> 1) & 3) << 4);
        gload16(gX + (size_t)(c0 + row) * KPB + kbs, (char*)&As[0][0] + wid * 2048 + j * 1024);
        gload16(gX + (size_t)(d0 + row) * KPB + kbs, (char*)&Bs[0][0] + wid * 2048 + j * 1024);
    }
    __syncthreads();

    for (int ks = 0; ks < 23; ++ks) {
        if (ks < 22) {
            int koff = (ks + 1) * 64;
            #pragma unroll
            for (int j = 0; j < 2; ++j) {
                int s = s0 + j * 1024;
                int row = s >> 6, kbs = (s & 63) ^ (((row >> 1) & 3) << 4);
                gload16(gX + (size_t)(c0 + row) * KPB + koff + kbs,
                        (char*)&As[buf ^ 1][0] + wid * 2048 + j * 1024);
                gload16(gX + (size_t)(d0 + row) * KPB + koff + kbs,
                        (char*)&Bs[buf ^ 1][0] + wid * 2048 + j * 1024);
            }
        }
        const char* Ab = (const char*)&As[buf][0];
        const char* Bb = (const char*)&Bs[buf][0];
        int kread = (g4 * 16) ^ swz;
        short8 a[4], b[4];
        #pragma unroll
        for (int mi = 0; mi < 4; ++mi)
            a[mi] = *(const short8*)(Ab + (wr * 64 + mi * 16 + rl) * 64 + kread);
        #pragma unroll
        for (int ni = 0; ni < 4; ++ni)
            b[ni] = *(const short8*)(Bb + (wc * 64 + ni * 16 + rl) * 64 + kread);
        #pragma unroll
        for (int mi = 0; mi < 4; ++mi)
            #pragma unroll
            for (int ni = 0; ni < 4; ++ni)
                acc[mi][ni] = __builtin_amdgcn_mfma_f32_16x16x32_bf16(
                    a[mi], b[ni], acc[mi][ni], 0, 0, 0);
        __syncthreads();
        buf ^= 1;
    }

    const float inv = 1.0f / (NSAMP - 1);
    #pragma unroll
    for (int mi = 0; mi < 4; ++mi)
        #pragma unroll
        for (int r = 0; r < 4; ++r) {
            int c = c0 + wr * 64 + mi * 16 + g4 * 4 + r;
            #pragma unroll
            for (int ni = 0; ni < 4; ++ni) {
                int d = d0 + wc * 64 + ni * 16 + rl;
                atomicAdd(&covf[((size_t)w * CN + c) * CN + d], acc[mi][ni][r] * inv);
            }
        }
}

// ---------------- covf (lower-triangle blocks) -> covb bf16, symmetrized full ----------------
__global__ void cov2b_kernel(const float* __restrict__ covf, u16* __restrict__ covb) {
    int i = blockIdx.x * 256 + threadIdx.x;        // w*CN*CN + c*CN + d
    int w = i >> 18;
    int cd = i & ((1 << 18) - 1);
    int c = cd >> 9, d = cd & 511;
    int cb = c >> 7, db = d >> 7;
    size_t src;
    if (cb >= db) src = ((size_t)w << 18) + ((size_t)c << 9) + d;
    else          src = ((size_t)w << 18) + ((size_t)d << 9) + c;   // mirror from lower block
    covb[i] = f2b(covf[src]);
}

// ---------------- transpose+center x1 -> Abf[(q*441+i)][c] bf16 (packed rows) ----------------
__global__ __launch_bounds__(256) void qtrans_kernel(const float* __restrict__ x1,
                                                     u16* __restrict__ Abf) {
    __shared__ u16 S[512][72];
    __shared__ float qm[64];
    int c0 = blockIdx.x * 64;
    int q  = blockIdx.y;
    int t = threadIdx.x;
    int lane = t & 63, cq = t >> 6;

    for (int cc = cq; cc < 64; cc += 4) {
        int c = c0 + cc;
        const float* p = x1 + ((size_t)q * CN + c) * HWN;
        float s = 0.f;
        for (int ic = 0; ic < 8; ++ic) {
            int i = ic * 64 + lane;
            float v = (i < HWN) ? p[i] : 0.f;
            s += v;
            S[i][cc] = f2b(v);
        }
        #pragma unroll
        for (int off = 32; off > 0; off >>= 1) s += __shfl_down(s, off);
        if (lane == 0) qm[cc] = s * (1.0f / HWN);
    }
    __syncthreads();

    int coct = t & 7;
    for (int p = 0; p < 16; ++p) {
        int il = p * 32 + (t >> 3);
        if (il >= HWN) continue;
        short8 v = *(const short8*)(&S[il][coct * 8]);
        short8 o;
        #pragma unroll
        for (int j = 0; j < 8; ++j) {
            float f = b2f((u16)v[j]) - qm[coct * 8 + j];
            o[j] = (short)f2b(f);
        }
        *(short8*)(Abf + ((size_t)(q * HWN + il)) * CN + c0 + coct * 8) = o;
    }
}

// ---------------- init: zero simws + covf + Abf pad rows ----------------
__global__ void init2_kernel(float* __restrict__ simws, float* __restrict__ covf,
                             u32* __restrict__ AbfPad32) {
    int tid = blockIdx.x * blockDim.x + threadIdx.x;
    int stride = gridDim.x * blockDim.x;
    int nsim = WAYN * MPAD2;
    for (int i = tid; i < nsim; i += stride) simws[i] = 0.f;
    int ncov = WAYN * CN * CN;
    for (int i = tid; i < ncov; i += stride) covf[i] = 0.f;
    int npadw = (MPAD2 - MROWS) * CN / 2;
    for (int i = tid; i < npadw; i += stride) AbfPad32[i] = 0;
}

// ---------------- main: 128x128 tile, 4 waves, 3 blocks/CU, block-symmetric 6 sub-GEMMs ----------------
// One block per (m-tile, w). sim = q0^T C00 q0 + q1^T C11 q1 + 2 q0^T C01 q1:
// sp tables (b1=K-half, dbase=N 128-slice, wgt): (0,0,1)(0,128,1)(1,256,1)(1,384,1)
// (0,256,2)(0,384,2). 48 chunks of K=32 (0.75x FLOPs), one prologue, per-sp register
// drain into simreg (no extra barriers). r14's proven chunk body/swizzle/ring-2.
__global__ __launch_bounds__(256, 3) void gemm128s_kernel(const u16* __restrict__ Abf,
                                                          const u16* __restrict__ covb,
                                                          float* __restrict__ simws) {
    __shared__ __align__(16) u16 As[2][128 * 32];
    __shared__ __align__(16) u16 Bs[2][128 * 32];
    __shared__ float simpart[128 * 3];

    int x = blockIdx.x & 7;
    int l = blockIdx.x >> 3;
    int g = l / 5;
    int m = x * 65 + g;
    if (m >= MT128) return;
    int w = l - g * 5;
    int r0 = m * 128;

    int t = threadIdx.x;
    int lane = t & 63, wid = t >> 6;
    int wr = wid >> 1, wc = wid & 1;        // 2M x 2N waves, wave tile 64x64
    int rl = lane & 15, g4 = lane >> 4;
    int swz = ((rl >> 1) & 3) << 4;
    int kread = (g4 * 16) ^ swz;

    const char* gA = (const char*)(Abf + (size_t)r0 * CN);        // row stride 1024 B
    const char* gBw = (const char*)covb + (size_t)w * 524288;     // row stride 1024 B

    const int b1tab[6] = {0, 0, 1, 1, 0, 0};            // K half
    const int dbtab[6] = {0, 128, 256, 384, 256, 384};  // d base

    f32x4 acc[4][4];
    float simreg[16];
    #pragma unroll
    for (int i = 0; i < 16; ++i) simreg[i] = 0.f;
    #pragma unroll
    for (int mi = 0; mi < 4; ++mi)
        #pragma unroll
        for (int ni = 0; ni < 4; ++ni)
            acc[mi][ni] = (f32x4){0.f, 0.f, 0.f, 0.f};

    // stage global chunk gc (sp = gc>>3, kc = gc&7) into slot gc&1: 2 A + 2 B gload16/thread
    auto stage_chunk = [&](int gc) {
        int sp = gc >> 3, kc = gc & 7;
        int slot = gc & 1;
        int kbyte = b1tab[sp] * 512 + kc * 64;
        int db = dbtab[sp];
        #pragma unroll
        for (int j = 0; j < 2; ++j) {
            int off = j * 4096 + t * 16;
            int row = off >> 6;
            int kbs = (off & 63) ^ (((row >> 1) & 3) << 4);
            gload16(gA + (size_t)row * 1024 + kbyte + kbs, (char*)&As[slot][0] + off);
            gload16(gBw + (size_t)(db + row) * 1024 + kbyte + kbs, (char*)&Bs[slot][0] + off);
        }
    };

    // merged chunk body (r14-proven): 8 ds_reads (b/a interleaved) then 16 MFMA
    auto do_chunk = [&](int gc) {
        const char* Ab = (const char*)&As[gc & 1][0];
        const char* Bb = (const char*)&Bs[gc & 1][0];
        short8 a[4], b[4];
        #pragma unroll
        for (int ni = 0; ni < 4; ++ni) {
            b[ni] = *(const short8*)(Bb + (wc * 64 + ni * 16 + rl) * 64 + kread);
            a[ni] = *(const short8*)(Ab + (wr * 64 + ni * 16 + rl) * 64 + kread);
        }
        __builtin_amdgcn_s_setprio(1);
        #pragma unroll
        for (int mi = 0; mi < 4; ++mi)
            #pragma unroll
            for (int ni = 0; ni < 4; ++ni)
                acc[mi][ni] = __builtin_amdgcn_mfma_f32_16x16x32_bf16(
                    a[mi], b[ni], acc[mi][ni], 0, 0, 0);
        __builtin_amdgcn_s_setprio(0);
    };

    stage_chunk(0);

    #pragma unroll 1
    for (int gc = 0; gc < 48; ++gc) {
        asm volatile("s_waitcnt vmcnt(0)" ::: "memory");   // chunk-gc loads landed
        __builtin_amdgcn_s_barrier();
        asm volatile("" ::: "memory");
        if (gc < 47) stage_chunk(gc + 1);                  // depth-1 prefetch into other slot
        do_chunk(gc);
        if ((gc & 7) == 7) {
            // sub-pass epilogue: drain acc into simreg, reset acc (no LDS, no barrier)
            int sp = gc >> 3;
            int db = dbtab[sp];
            float wgt = (sp >= 4) ? 2.f : 1.f;
            #pragma unroll
            for (int mi = 0; mi < 4; ++mi) {
                #pragma unroll
                for (int r = 0; r < 4; ++r) {
                    int Rl = wr * 64 + mi * 16 + g4 * 4 + r;
                    size_t Rg = (size_t)r0 + Rl;
                    float s = 0.f;
                    #pragma unroll
                    for (int ni = 0; ni < 4; ++ni) {
                        int d = db + wc * 64 + ni * 16 + rl;
                        s += acc[mi][ni][r] * b2f(Abf[Rg * CN + d]);
                    }
                    simreg[mi * 4 + r] += wgt * s;
                }
            }
            #pragma unroll
            for (int mi = 0; mi < 4; ++mi)
                #pragma unroll
                for (int ni = 0; ni < 4; ++ni)
                    acc[mi][ni] = (f32x4){0.f, 0.f, 0.f, 0.f};
        }
    }

    // final reduce: simreg over 16-lane groups -> simpart -> atomicAdd
    #pragma unroll
    for (int idx = 0; idx < 16; ++idx) {
        float v = simreg[idx];
        v += __shfl_xor(v, 1);
        v += __shfl_xor(v, 2);
        v += __shfl_xor(v, 4);
        v += __shfl_xor(v, 8);
        int mi = idx >> 2, r = idx & 3;
        int Rl = wr * 64 + mi * 16 + g4 * 4 + r;
        if (rl == 0) simpart[Rl * 3 + wc] = v;
    }
    __syncthreads();
    if (t < 128) {
        float v = simpart[t * 3 + 0] + simpart[t * 3 + 1];
        atomicAdd(&simws[(size_t)w * MPAD2 + r0 + t], v);
    }
}

// ---------------- finish: act + conv dot + bias -> scores ----------------
__global__ void finish_kernel(const float* __restrict__ simws,
                              const float* __restrict__ conv_w,
                              const float* __restrict__ conv_b,
                              float* __restrict__ scores) {
    int q = blockIdx.x, w = blockIdx.y;
    int t = threadIdx.x;    // 128
    const float* sp = simws + (size_t)w * MPAD2 + q * HWN;
    float s = 0.f;
    for (int i = t; i < HWN; i += 128) {
        float v = sp[i];
        float a = (v >= 0.f) ? v : 0.2f * v;
        s += a * conv_w[i];
    }
    __shared__ float red[2];
    #pragma unroll
    for (int off = 32; off > 0; off >>= 1) s += __shfl_down(s, off);
    if ((t & 63) == 0) red[t >> 6] = s;
    __syncthreads();
    if (t == 0) scores[q * WAYN + w] = red[0] + red[1] + conv_b[0];
}

extern "C" void kernel_launch(void* const* d_in, const int* in_sizes, int n_in,
                              void* d_out, int out_size, void* d_ws, size_t ws_size,
                              hipStream_t stream) {
    const float* x1     = (const float*)d_in[0];
    const float* x2     = (const float*)d_in[1];
    const float* conv_w = (const float*)d_in[2];
    const float* conv_b = (const float*)d_in[3];
    float* scores = (float*)d_out;

    char* ws = (char*)d_ws;
    u16* covb    = (u16*)ws;                               // 2,621,440 B
    float* simws = (float*)(ws + 2631680);                 // 1,326,080 B
    float* covf  = (float*)(ws + 3957760);                 // 5,242,880 B
    // x2c aliases head of Abf (covmfma reads x2c before qtrans writes Abf)
    u16* x2c     = (u16*)(ws + 9200640);                   // 11,304,960 B
    u16* Abf     = (u16*)(ws + 9200640);                   // 66304*512*2 = 67,895,296 B

    wx2c_kernel<<<WAYN * CN, 64, 0, stream>>>(x2, x2c);
    init2_kernel<<<256, 256, 0, stream>>>(simws, covf, (u32*)(Abf + (size_t)MROWS * CN));
    covmfma_kernel<<<dim3(10, 1, WAYN * 3), 256, 0, stream>>>(x2c, covf);
    cov2b_kernel<<<WAYN * CN * CN / 256, 256, 0, stream>>>(covf, covb);
    qtrans_kernel<<<dim3(8, QN), 256, 0, stream>>>(x1, Abf);
    gemm128s_kernel<<<8 * 65 * 5, 256, 0, stream>>>(Abf, covb, simws);
    finish_kernel<<<dim3(QN, WAYN), 128, 0, stream>>>(simws, conv_w, conv_b, scores);
}

// Round 16
// 293.232 us; speedup vs baseline: 1.5184x; 1.0413x over previous
//
#include <hip/hip_runtime.h>
#include <hip/hip_bf16.h>

#define QN 150
#define CN 512
#define HWN 441
#define WAYN 5
#define SHOTN 5
#define NSAMP 2205           // SHOT*HW
#define MROWS (QN * HWN)     // 66150 packed rows
#define MT128 517            // ceil(66150/128)
#define MPAD2 66304
#define KP 2208              // cov K padded (32*69)
#define KPB (KP * 2)         // row bytes of x2c

typedef unsigned short u16;
typedef unsigned int u32;
typedef __attribute__((ext_vector_type(8))) short short8;
typedef __attribute__((ext_vector_type(4))) float f32x4;

__device__ __forceinline__ u16 f2b(float f) {
    return __builtin_bit_cast(u16, __float2bfloat16(f));
}
__device__ __forceinline__ float b2f(u16 h) {
    u32 u = ((u32)h) << 16;
    return __builtin_bit_cast(float, u);
}

__device__ __forceinline__ void gload16(const void* g, void* l) {
    __builtin_amdgcn_global_load_lds(
        (const __attribute__((address_space(1))) unsigned int*)g,
        (__attribute__((address_space(3))) unsigned int*)l, 16, 0, 0);
}

// pair index p in [0,10) -> (lo, hi) with lo <= hi over 4 blocks of 128
__device__ __forceinline__ void pair_decode(int p, int& lo, int& hi) {
    hi = (p >= 6) ? 3 : (p >= 3 ? 2 : (p >= 1 ? 1 : 0));
    int tri = (hi == 3) ? 6 : (hi == 2 ? 3 : (hi == 1 ? 1 : 0));
    lo = p - tri;
}

// ---------------- fused: per-(way,channel) mean + center x2 -> bf16 x2c[w][c][k] ----------------
__global__ void wx2c_kernel(const float* __restrict__ x2, u16* __restrict__ x2c) {
    int b = blockIdx.x;             // w*512 + c
    int w = b >> 9, c = b & 511;
    int lane = threadIdx.x;         // 64
    float s = 0.f;
    #pragma unroll
    for (int sh = 0; sh < SHOTN; ++sh) {
        const float* p = x2 + ((size_t)((w * SHOTN + sh) * CN + c)) * HWN;
        for (int i = lane; i < HWN; i += 64) s += p[i];
    }
    #pragma unroll
    for (int off = 32; off > 0; off >>= 1) s += __shfl_down(s, off);
    float m = __shfl(s, 0) * (1.0f / NSAMP);

    u16* dst = x2c + ((size_t)(w * CN + c)) * KP;
    #pragma unroll
    for (int sh = 0; sh < SHOTN; ++sh) {
        const float* p = x2 + ((size_t)((w * SHOTN + sh) * CN + c)) * HWN;
        for (int i = lane; i < HWN; i += 64) dst[sh * HWN + i] = f2b(p[i] - m);
    }
    if (lane < (KP - NSAMP)) dst[NSAMP + lane] = 0;
}

// ---------------- cov MFMA split-K, lower-triangle 128-blocks only ----------------
__global__ __launch_bounds__(256, 2) void covmfma_kernel(const u16* __restrict__ x2c,
                                                         float* __restrict__ covf) {
    __shared__ __align__(16) u16 As[2][128 * 32];
    __shared__ __align__(16) u16 Bs[2][128 * 32];
    int z  = blockIdx.z;
    int w  = z / 3, ksp = z - w * 3;
    int dblk, cblk;
    pair_decode(blockIdx.x, dblk, cblk);    // cblk >= dblk
    int c0 = cblk * 128;
    int d0 = dblk * 128;
    int t = threadIdx.x;
    int lane = t & 63, wid = t >> 6;
    int wr = wid >> 1, wc = wid & 1;
    int rl = lane & 15, g4 = lane >> 4;
    int swz = ((rl >> 1) & 3) << 4;
    int s0 = wid * 2048 + lane * 16;

    const char* gX = (const char*)(x2c + (size_t)w * CN * KP) + ksp * 1472; // 736 elems

    f32x4 acc[4][4];
    #pragma unroll
    for (int mi = 0; mi < 4; ++mi)
        #pragma unroll
        for (int ni = 0; ni < 4; ++ni)
            acc[mi][ni] = (f32x4){0.f, 0.f, 0.f, 0.f};

    int buf = 0;
    #pragma unroll
    for (int j = 0; j < 2; ++j) {
        int s = s0 + j * 1024;
        int row = s >> 6, kbs = (s & 63) ^ (((row >> 1) & 3) << 4);
        gload16(gX + (size_t)(c0 + row) * KPB + kbs, (char*)&As[0][0] + wid * 2048 + j * 1024);
        gload16(gX + (size_t)(d0 + row) * KPB + kbs, (char*)&Bs[0][0] + wid * 2048 + j * 1024);
    }
    __syncthreads();

    for (int ks = 0; ks < 23; ++ks) {
        if (ks < 22) {
            int koff = (ks + 1) * 64;
            #pragma unroll
            for (int j = 0; j < 2; ++j) {
                int s = s0 + j * 1024;
                int row = s >> 6, kbs = (s & 63) ^ (((row >> 1) & 3) << 4);
                gload16(gX + (size_t)(c0 + row) * KPB + koff + kbs,
                        (char*)&As[buf ^ 1][0] + wid * 2048 + j * 1024);
                gload16(gX + (size_t)(d0 + row) * KPB + koff + kbs,
                        (char*)&Bs[buf ^ 1][0] + wid * 2048 + j * 1024);
            }
        }
        const char* Ab = (const char*)&As[buf][0];
        const char* Bb = (const char*)&Bs[buf][0];
        int kread = (g4 * 16) ^ swz;
        short8 a[4], b[4];
        #pragma unroll
        for (int mi = 0; mi < 4; ++mi)
            a[mi] = *(const short8*)(Ab + (wr * 64 + mi * 16 + rl) * 64 + kread);
        #pragma unroll
        for (int ni = 0; ni < 4; ++ni)
            b[ni] = *(const short8*)(Bb + (wc * 64 + ni * 16 + rl) * 64 + kread);
        #pragma unroll
        for (int mi = 0; mi < 4; ++mi)
            #pragma unroll
            for (int ni = 0; ni < 4; ++ni)
                acc[mi][ni] = __builtin_amdgcn_mfma_f32_16x16x32_bf16(
                    a[mi], b[ni], acc[mi][ni], 0, 0, 0);
        __syncthreads();
        buf ^= 1;
    }

    const float inv = 1.0f / (NSAMP - 1);
    #pragma unroll
    for (int mi = 0; mi < 4; ++mi)
        #pragma unroll
        for (int r = 0; r < 4; ++r) {
            int c = c0 + wr * 64 + mi * 16 + g4 * 4 + r;
            #pragma unroll
            for (int ni = 0; ni < 4; ++ni) {
                int d = d0 + wc * 64 + ni * 16 + rl;
                atomicAdd(&covf[((size_t)w * CN + c) * CN + d], acc[mi][ni][r] * inv);
            }
        }
}

// ---------------- covf (lower-tri blocks) -> covb bf16, symmetrized; cross block pre-scaled x2 ----------------
__global__ void cov2b_kernel(const float* __restrict__ covf, u16* __restrict__ covb) {
    int i = blockIdx.x * 256 + threadIdx.x;        // w*CN*CN + c*CN + d   (c = B row = output-d, d = k)
    int w = i >> 18;
    int cd = i & ((1 << 18) - 1);
    int c = cd >> 9, d = cd & 511;
    int cb = c >> 7, db = d >> 7;
    size_t src;
    if (cb >= db) src = ((size_t)w << 18) + ((size_t)c << 9) + d;
    else          src = ((size_t)w << 18) + ((size_t)d << 9) + c;   // mirror from lower block
    float v = covf[src];
    if (c >= 256 && d < 256) v *= 2.f;     // fold symmetry weight into cross block (rows d>=256, k<256)
    covb[i] = f2b(v);
}

// ---------------- transpose+center x1 -> Abf[(q*441+i)][c] bf16 (packed rows) ----------------
__global__ __launch_bounds__(256) void qtrans_kernel(const float* __restrict__ x1,
                                                     u16* __restrict__ Abf) {
    __shared__ u16 S[512][72];
    __shared__ float qm[64];
    int c0 = blockIdx.x * 64;
    int q  = blockIdx.y;
    int t = threadIdx.x;
    int lane = t & 63, cq = t >> 6;

    for (int cc = cq; cc < 64; cc += 4) {
        int c = c0 + cc;
        const float* p = x1 + ((size_t)q * CN + c) * HWN;
        float s = 0.f;
        for (int ic = 0; ic < 8; ++ic) {
            int i = ic * 64 + lane;
            float v = (i < HWN) ? p[i] : 0.f;
            s += v;
            S[i][cc] = f2b(v);
        }
        #pragma unroll
        for (int off = 32; off > 0; off >>= 1) s += __shfl_down(s, off);
        if (lane == 0) qm[cc] = s * (1.0f / HWN);
    }
    __syncthreads();

    int coct = t & 7;
    for (int p = 0; p < 16; ++p) {
        int il = p * 32 + (t >> 3);
        if (il >= HWN) continue;
        short8 v = *(const short8*)(&S[il][coct * 8]);
        short8 o;
        #pragma unroll
        for (int j = 0; j < 8; ++j) {
            float f = b2f((u16)v[j]) - qm[coct * 8 + j];
            o[j] = (short)f2b(f);
        }
        *(short8*)(Abf + ((size_t)(q * HWN + il)) * CN + c0 + coct * 8) = o;
    }
}

// ---------------- init: zero covf + Abf pad rows (simws now plain-stored by gemm) ----------------
__global__ void init2_kernel(float* __restrict__ covf, u32* __restrict__ AbfPad32) {
    int tid = blockIdx.x * blockDim.x + threadIdx.x;
    int stride = gridDim.x * blockDim.x;
    int ncov = WAYN * CN * CN;
    for (int i = tid; i < ncov; i += stride) covf[i] = 0.f;
    int npadw = (MPAD2 - MROWS) * CN / 2;
    for (int i = tid; i < npadw; i += stride) AbfPad32[i] = 0;
}

// ---------------- main: 128x128 tile, 4 waves, 3 blocks/CU, 4 block-symmetric sub-passes ----------------
// One block per (m-tile, w). With cross block pre-scaled 2x in covb:
// sp0: d=[0,128)   K=[0,256)   chunks 0-7
// sp1: d=[128,256) K=[0,256)   chunks 8-15
// sp2: d=[256,384) K=[0,512)   chunks 16-31
// sp3: d=[384,512) K=[0,512)   chunks 32-47
// 48 chunks (0.75x FLOPs), one prologue, per-sp register drain (weight 1), plain simws store.
__global__ __launch_bounds__(256, 3) void gemm128s_kernel(const u16* __restrict__ Abf,
                                                          const u16* __restrict__ covb,
                                                          float* __restrict__ simws) {
    __shared__ __align__(16) u16 As[2][128 * 32];
    __shared__ __align__(16) u16 Bs[2][128 * 32];
    __shared__ float simpart[128 * 3];

    int x = blockIdx.x & 7;
    int l = blockIdx.x >> 3;
    int g = l / 5;
    int m = x * 65 + g;
    if (m >= MT128) return;
    int w = l - g * 5;
    int r0 = m * 128;

    int t = threadIdx.x;
    int lane = t & 63, wid = t >> 6;
    int wr = wid >> 1, wc = wid & 1;        // 2M x 2N waves, wave tile 64x64
    int rl = lane & 15, g4 = lane >> 4;
    int swz = ((rl >> 1) & 3) << 4;
    int kread = (g4 * 16) ^ swz;

    const char* gA = (const char*)(Abf + (size_t)r0 * CN);        // row stride 1024 B
    const char* gBw = (const char*)covb + (size_t)w * 524288;     // row stride 1024 B

    f32x4 acc[4][4];
    float simreg[16];
    #pragma unroll
    for (int i = 0; i < 16; ++i) simreg[i] = 0.f;
    #pragma unroll
    for (int mi = 0; mi < 4; ++mi)
        #pragma unroll
        for (int ni = 0; ni < 4; ++ni)
            acc[mi][ni] = (f32x4){0.f, 0.f, 0.f, 0.f};

    // gc -> (sp, kc): sp0 gc0-7, sp1 gc8-15, sp2 gc16-31, sp3 gc32-47
    auto sp_of = [](int gc) { return (gc >= 32) ? 3 : (gc >= 16) ? 2 : (gc >> 3); };
    auto kc_of = [](int gc, int sp) {
        const int st[4] = {0, 8, 16, 32};
        return gc - st[sp];
    };
    const int dbtab[4] = {0, 128, 256, 384};

    // stage global chunk gc into slot gc&1: 2 A + 2 B gload16/thread
    auto stage_chunk = [&](int gc) {
        int sp = sp_of(gc);
        int kbyte = kc_of(gc, sp) * 64;
        int db = dbtab[sp];
        int slot = gc & 1;
        #pragma unroll
        for (int j = 0; j < 2; ++j) {
            int off = j * 4096 + t * 16;
            int row = off >> 6;
            int kbs = (off & 63) ^ (((row >> 1) & 3) << 4);
            gload16(gA + (size_t)row * 1024 + kbyte + kbs, (char*)&As[slot][0] + off);
            gload16(gBw + (size_t)(db + row) * 1024 + kbyte + kbs, (char*)&Bs[slot][0] + off);
        }
    };

    // merged chunk body (r14-proven): 8 ds_reads (b/a interleaved) then 16 MFMA
    auto do_chunk = [&](int gc) {
        const char* Ab = (const char*)&As[gc & 1][0];
        const char* Bb = (const char*)&Bs[gc & 1][0];
        short8 a[4], b[4];
        #pragma unroll
        for (int ni = 0; ni < 4; ++ni) {
            b[ni] = *(const short8*)(Bb + (wc * 64 + ni * 16 + rl) * 64 + kread);
            a[ni] = *(const short8*)(Ab + (wr * 64 + ni * 16 + rl) * 64 + kread);
        }
        __builtin_amdgcn_s_setprio(1);
        #pragma unroll
        for (int mi = 0; mi < 4; ++mi)
            #pragma unroll
            for (int ni = 0; ni < 4; ++ni)
                acc[mi][ni] = __builtin_amdgcn_mfma_f32_16x16x32_bf16(
                    a[mi], b[ni], acc[mi][ni], 0, 0, 0);
        __builtin_amdgcn_s_setprio(0);
    };

    stage_chunk(0);

    #pragma unroll 1
    for (int gc = 0; gc < 48; ++gc) {
        asm volatile("s_waitcnt vmcnt(0)" ::: "memory");   // chunk-gc loads landed
        __builtin_amdgcn_s_barrier();
        asm volatile("" ::: "memory");
        if (gc < 47) stage_chunk(gc + 1);                  // depth-1 prefetch into other slot
        do_chunk(gc);
        if (gc == 7 || gc == 15 || gc == 31 || gc == 47) {
            // sub-pass epilogue: drain acc into simreg, reset acc (no LDS, no barrier)
            int db = dbtab[sp_of(gc)];
            #pragma unroll
            for (int mi = 0; mi < 4; ++mi) {
                #pragma unroll
                for (int r = 0; r < 4; ++r) {
                    int Rl = wr * 64 + mi * 16 + g4 * 4 + r;
                    size_t Rg = (size_t)r0 + Rl;
                    float s = 0.f;
                    #pragma unroll
                    for (int ni = 0; ni < 4; ++ni) {
                        int d = db + wc * 64 + ni * 16 + rl;
                        s += acc[mi][ni][r] * b2f(Abf[Rg * CN + d]);
                    }
                    simreg[mi * 4 + r] += s;
                }
            }
            #pragma unroll
            for (int mi = 0; mi < 4; ++mi)
                #pragma unroll
                for (int ni = 0; ni < 4; ++ni)
                    acc[mi][ni] = (f32x4){0.f, 0.f, 0.f, 0.f};
        }
    }

    // final reduce: simreg over 16-lane groups -> simpart -> plain store (one block owns these rows)
    #pragma unroll
    for (int idx = 0; idx < 16; ++idx) {
        float v = simreg[idx];
        v += __shfl_xor(v, 1);
        v += __shfl_xor(v, 2);
        v += __shfl_xor(v, 4);
        v += __shfl_xor(v, 8);
        int mi = idx >> 2, r = idx & 3;
        int Rl = wr * 64 + mi * 16 + g4 * 4 + r;
        if (rl == 0) simpart[Rl * 3 + wc] = v;
    }
    __syncthreads();
    if (t < 128) {
        float v = simpart[t * 3 + 0] + simpart[t * 3 + 1];
        simws[(size_t)w * MPAD2 + r0 + t] = v;
    }
}

// ---------------- finish: act + conv dot + bias -> scores ----------------
__global__ void finish_kernel(const float* __restrict__ simws,
                              const float* __restrict__ conv_w,
                              const float* __restrict__ conv_b,
                              float* __restrict__ scores) {
    int q = blockIdx.x, w = blockIdx.y;
    int t = threadIdx.x;    // 128
    const float* sp = simws + (size_t)w * MPAD2 + q * HWN;
    float s = 0.f;
    for (int i = t; i < HWN; i += 128) {
        float v = sp[i];
        float a = (v >= 0.f) ? v : 0.2f * v;
        s += a * conv_w[i];
    }
    __shared__ float red[2];
    #pragma unroll
    for (int off = 32; off > 0; off >>= 1) s += __shfl_down(s, off);
    if ((t & 63) == 0) red[t >> 6] = s;
    __syncthreads();
    if (t == 0) scores[q * WAYN + w] = red[0] + red[1] + conv_b[0];
}

extern "C" void kernel_launch(void* const* d_in, const int* in_sizes, int n_in,
                              void* d_out, int out_size, void* d_ws, size_t ws_size,
                              hipStream_t stream) {
    const float* x1     = (const float*)d_in[0];
    const float* x2     = (const float*)d_in[1];
    const float* conv_w = (const float*)d_in[2];
    const float* conv_b = (const float*)d_in[3];
    float* scores = (float*)d_out;

    char* ws = (char*)d_ws;
    u16* covb    = (u16*)ws;                               // 2,621,440 B
    float* simws = (float*)(ws + 2631680);                 // 1,326,080 B
    float* covf  = (float*)(ws + 3957760);                 // 5,242,880 B
    // x2c aliases head of Abf (covmfma reads x2c before qtrans writes Abf)
    u16* x2c     = (u16*)(ws + 9200640);                   // 11,304,960 B
    u16* Abf     = (u16*)(ws + 9200640);                   // 66304*512*2 = 67,895,296 B

    wx2c_kernel<<<WAYN * CN, 64, 0, stream>>>(x2, x2c);
    init2_kernel<<<256, 256, 0, stream>>>(covf, (u32*)(Abf + (size_t)MROWS * CN));
    covmfma_kernel<<<dim3(10, 1, WAYN * 3), 256, 0, stream>>>(x2c, covf);
    cov2b_kernel<<<WAYN * CN * CN / 256, 256, 0, stream>>>(covf, covb);
    qtrans_kernel<<<dim3(8, QN), 256, 0, stream>>>(x1, Abf);
    gemm128s_kernel<<<8 * 65 * 5, 256, 0, stream>>>(Abf, covb, simws);
    finish_kernel<<<dim3(QN, WAYN), 128, 0, stream>>>(simws, conv_w, conv_b, scores);
}

// Round 17
// 282.638 us; speedup vs baseline: 1.5753x; 1.0375x over previous
//
#include <hip/hip_runtime.h>
#include <hip/hip_bf16.h>

#define QN 150
#define CN 512
#define HWN 441
#define WAYN 5
#define SHOTN 5
#define NSAMP 2205           // SHOT*HW
#define MROWS (QN * HWN)     // 66150 packed rows
#define MT128 517            // ceil(66150/128)
#define MPAD2 66304
#define KP 2208              // cov K padded (32*69)
#define KPB (KP * 2)         // row bytes of x2c

typedef unsigned short u16;
typedef unsigned int u32;
typedef __attribute__((ext_vector_type(8))) short short8;
typedef __attribute__((ext_vector_type(4))) float f32x4;

__device__ __forceinline__ u16 f2b(float f) {
    return __builtin_bit_cast(u16, __float2bfloat16(f));
}
__device__ __forceinline__ float b2f(u16 h) {
    u32 u = ((u32)h) << 16;
    return __builtin_bit_cast(float, u);
}

__device__ __forceinline__ void gload16(const void* g, void* l) {
    __builtin_amdgcn_global_load_lds(
        (const __attribute__((address_space(1))) unsigned int*)g,
        (__attribute__((address_space(3))) unsigned int*)l, 16, 0, 0);
}

// pair index p in [0,10) -> (lo, hi) with lo <= hi over 4 blocks of 128
__device__ __forceinline__ void pair_decode(int p, int& lo, int& hi) {
    hi = (p >= 6) ? 3 : (p >= 3 ? 2 : (p >= 1 ? 1 : 0));
    int tri = (hi == 3) ? 6 : (hi == 2 ? 3 : (hi == 1 ? 1 : 0));
    lo = p - tri;
}

// ---------------- fused: per-(way,channel) mean + center x2 -> bf16 x2c[w][c][k] ----------------
__global__ void wx2c_kernel(const float* __restrict__ x2, u16* __restrict__ x2c) {
    int b = blockIdx.x;             // w*512 + c
    int w = b >> 9, c = b & 511;
    int lane = threadIdx.x;         // 64
    float s = 0.f;
    #pragma unroll
    for (int sh = 0; sh < SHOTN; ++sh) {
        const float* p = x2 + ((size_t)((w * SHOTN + sh) * CN + c)) * HWN;
        for (int i = lane; i < HWN; i += 64) s += p[i];
    }
    #pragma unroll
    for (int off = 32; off > 0; off >>= 1) s += __shfl_down(s, off);
    float m = __shfl(s, 0) * (1.0f / NSAMP);

    u16* dst = x2c + ((size_t)(w * CN + c)) * KP;
    #pragma unroll
    for (int sh = 0; sh < SHOTN; ++sh) {
        const float* p = x2 + ((size_t)((w * SHOTN + sh) * CN + c)) * HWN;
        for (int i = lane; i < HWN; i += 64) dst[sh * HWN + i] = f2b(p[i] - m);
    }
    if (lane < (KP - NSAMP)) dst[NSAMP + lane] = 0;
}

// ---------------- cov MFMA split-K, lower-triangle 128-blocks only ----------------
__global__ __launch_bounds__(256, 2) void covmfma_kernel(const u16* __restrict__ x2c,
                                                         float* __restrict__ covf) {
    __shared__ __align__(16) u16 As[2][128 * 32];
    __shared__ __align__(16) u16 Bs[2][128 * 32];
    int z  = blockIdx.z;
    int w  = z / 3, ksp = z - w * 3;
    int dblk, cblk;
    pair_decode(blockIdx.x, dblk, cblk);    // cblk >= dblk
    int c0 = cblk * 128;
    int d0 = dblk * 128;
    int t = threadIdx.x;
    int lane = t & 63, wid = t >> 6;
    int wr = wid >> 1, wc = wid & 1;
    int rl = lane & 15, g4 = lane >> 4;
    int swz = ((rl >> 1) & 3) << 4;
    int s0 = wid * 2048 + lane * 16;

    const char* gX = (const char*)(x2c + (size_t)w * CN * KP) + ksp * 1472; // 736 elems

    f32x4 acc[4][4];
    #pragma unroll
    for (int mi = 0; mi < 4; ++mi)
        #pragma unroll
        for (int ni = 0; ni < 4; ++ni)
            acc[mi][ni] = (f32x4){0.f, 0.f, 0.f, 0.f};

    int buf = 0;
    #pragma unroll
    for (int j = 0; j < 2; ++j) {
        int s = s0 + j * 1024;
        int row = s >> 6, kbs = (s & 63) ^ (((row >> 1) & 3) << 4);
        gload16(gX + (size_t)(c0 + row) * KPB + kbs, (char*)&As[0][0] + wid * 2048 + j * 1024);
        gload16(gX + (size_t)(d0 + row) * KPB + kbs, (char*)&Bs[0][0] + wid * 2048 + j * 1024);
    }
    __syncthreads();

    for (int ks = 0; ks < 23; ++ks) {
        if (ks < 22) {
            int koff = (ks + 1) * 64;
            #pragma unroll
            for (int j = 0; j < 2; ++j) {
                int s = s0 + j * 1024;
                int row = s >> 6, kbs = (s & 63) ^ (((row >> 1) & 3) << 4);
                gload16(gX + (size_t)(c0 + row) * KPB + koff + kbs,
                        (char*)&As[buf ^ 1][0] + wid * 2048 + j * 1024);
                gload16(gX + (size_t)(d0 + row) * KPB + koff + kbs,
                        (char*)&Bs[buf ^ 1][0] + wid * 2048 + j * 1024);
            }
        }
        const char* Ab = (const char*)&As[buf][0];
        const char* Bb = (const char*)&Bs[buf][0];
        int kread = (g4 * 16) ^ swz;
        short8 a[4], b[4];
        #pragma unroll
        for (int mi = 0; mi < 4; ++mi)
            a[mi] = *(const short8*)(Ab + (wr * 64 + mi * 16 + rl) * 64 + kread);
        #pragma unroll
        for (int ni = 0; ni < 4; ++ni)
            b[ni] = *(const short8*)(Bb + (wc * 64 + ni * 16 + rl) * 64 + kread);
        #pragma unroll
        for (int mi = 0; mi < 4; ++mi)
            #pragma unroll
            for (int ni = 0; ni < 4; ++ni)
                acc[mi][ni] = __builtin_amdgcn_mfma_f32_16x16x32_bf16(
                    a[mi], b[ni], acc[mi][ni], 0, 0, 0);
        __syncthreads();
        buf ^= 1;
    }

    const float inv = 1.0f / (NSAMP - 1);
    #pragma unroll
    for (int mi = 0; mi < 4; ++mi)
        #pragma unroll
        for (int r = 0; r < 4; ++r) {
            int c = c0 + wr * 64 + mi * 16 + g4 * 4 + r;
            #pragma unroll
            for (int ni = 0; ni < 4; ++ni) {
                int d = d0 + wc * 64 + ni * 16 + rl;
                atomicAdd(&covf[((size_t)w * CN + c) * CN + d], acc[mi][ni][r] * inv);
            }
        }
}

// ---------------- covf (lower-tri blocks) -> covb bf16, symmetrized; cross block pre-scaled x2 ----------------
__global__ void cov2b_kernel(const float* __restrict__ covf, u16* __restrict__ covb) {
    int i = blockIdx.x * 256 + threadIdx.x;        // w*CN*CN + c*CN + d   (c = B row = output-d, d = k)
    int w = i >> 18;
    int cd = i & ((1 << 18) - 1);
    int c = cd >> 9, d = cd & 511;
    int cb = c >> 7, db = d >> 7;
    size_t src;
    if (cb >= db) src = ((size_t)w << 18) + ((size_t)c << 9) + d;
    else          src = ((size_t)w << 18) + ((size_t)d << 9) + c;   // mirror from lower block
    float v = covf[src];
    if (c >= 256 && d < 256) v *= 2.f;     // fold symmetry weight into cross block
    covb[i] = f2b(v);
}

// ---------------- transpose+center x1 -> Abf[(q*441+i)][c] bf16 (packed rows) ----------------
__global__ __launch_bounds__(256) void qtrans_kernel(const float* __restrict__ x1,
                                                     u16* __restrict__ Abf) {
    __shared__ u16 S[512][72];
    __shared__ float qm[64];
    int c0 = blockIdx.x * 64;
    int q  = blockIdx.y;
    int t = threadIdx.x;
    int lane = t & 63, cq = t >> 6;

    for (int cc = cq; cc < 64; cc += 4) {
        int c = c0 + cc;
        const float* p = x1 + ((size_t)q * CN + c) * HWN;
        float s = 0.f;
        for (int ic = 0; ic < 8; ++ic) {
            int i = ic * 64 + lane;
            float v = (i < HWN) ? p[i] : 0.f;
            s += v;
            S[i][cc] = f2b(v);
        }
        #pragma unroll
        for (int off = 32; off > 0; off >>= 1) s += __shfl_down(s, off);
        if (lane == 0) qm[cc] = s * (1.0f / HWN);
    }
    __syncthreads();

    int coct = t & 7;
    for (int p = 0; p < 16; ++p) {
        int il = p * 32 + (t >> 3);
        if (il >= HWN) continue;
        short8 v = *(const short8*)(&S[il][coct * 8]);
        short8 o;
        #pragma unroll
        for (int j = 0; j < 8; ++j) {
            float f = b2f((u16)v[j]) - qm[coct * 8 + j];
            o[j] = (short)f2b(f);
        }
        *(short8*)(Abf + ((size_t)(q * HWN + il)) * CN + c0 + coct * 8) = o;
    }
}

// ---------------- init: zero simws + covf + Abf pad rows ----------------
__global__ void init2_kernel(float* __restrict__ simws, float* __restrict__ covf,
                             u32* __restrict__ AbfPad32) {
    int tid = blockIdx.x * blockDim.x + threadIdx.x;
    int stride = gridDim.x * blockDim.x;
    int nsim = WAYN * MPAD2;
    for (int i = tid; i < nsim; i += stride) simws[i] = 0.f;
    int ncov = WAYN * CN * CN;
    for (int i = tid; i < ncov; i += stride) covf[i] = 0.f;
    int npadw = (MPAD2 - MROWS) * CN / 2;
    for (int i = tid; i < npadw; i += stride) AbfPad32[i] = 0;
}

// ---------------- main: 128x128 tile, 4 waves, 3 blocks/CU, variable-K d-slice blocks ----------------
// One block per (m-tile, w, d-slice). With cross block pre-scaled 2x in covb:
//   d-slice 0: d=[0,128)   K=[0,256)  -> 8 chunks
//   d-slice 1: d=[128,256) K=[0,256)  -> 8 chunks
//   d-slice 2: d=[256,384) K=[0,512)  -> 16 chunks
//   d-slice 3: d=[384,512) K=[0,512)  -> 16 chunks
// 48 chunks per (m,w) total (0.75x FLOPs) spread over 4 blocks -> 10400 blocks, full
// occupancy rounds, single epilogue drain + atomicAdd per block (r14's exact shape).
__global__ __launch_bounds__(256, 3) void gemm128v_kernel(const u16* __restrict__ Abf,
                                                          const u16* __restrict__ covb,
                                                          float* __restrict__ simws) {
    __shared__ __align__(16) u16 As[2][128 * 32];
    __shared__ __align__(16) u16 Bs[2][128 * 32];
    __shared__ float simpart[128 * 3];

    int x = blockIdx.x & 7;
    int l = blockIdx.x >> 3;
    int g = l / 20;
    int m = x * 65 + g;
    if (m >= MT128) return;
    int inner = l - g * 20;
    int w  = inner % 5;
    int dsl = inner / 5;                 // 0..3
    int n0 = dsl * 128;
    int NCH = (dsl < 2) ? 8 : 16;        // K = 256 or 512
    int r0 = m * 128;

    int t = threadIdx.x;
    int lane = t & 63, wid = t >> 6;
    int wr = wid >> 1, wc = wid & 1;        // 2M x 2N waves, wave tile 64x64
    int rl = lane & 15, g4 = lane >> 4;
    int swz = ((rl >> 1) & 3) << 4;
    int kread = (g4 * 16) ^ swz;

    const char* gA = (const char*)(Abf + (size_t)r0 * CN);               // row stride 1024 B
    const char* gB = (const char*)(covb + ((size_t)w * CN + n0) * CN);   // row stride 1024 B

    f32x4 acc[4][4];
    #pragma unroll
    for (int mi = 0; mi < 4; ++mi)
        #pragma unroll
        for (int ni = 0; ni < 4; ++ni)
            acc[mi][ni] = (f32x4){0.f, 0.f, 0.f, 0.f};

    // stage chunk kc into slot kc&1: 2 A + 2 B gload16 per thread (8 KB each op)
    auto stage_chunk = [&](int kc) {
        int slot = kc & 1;
        int kbyte = kc * 64;
        #pragma unroll
        for (int j = 0; j < 2; ++j) {
            int off = j * 4096 + t * 16;
            int row = off >> 6;
            int kbs = (off & 63) ^ (((row >> 1) & 3) << 4);
            gload16(gA + (size_t)row * 1024 + kbyte + kbs, (char*)&As[slot][0] + off);
            gload16(gB + (size_t)row * 1024 + kbyte + kbs, (char*)&Bs[slot][0] + off);
        }
    };

    // merged chunk body (r14-proven): 8 ds_reads (b/a interleaved) then 16 MFMA
    auto do_chunk = [&](int c) {
        const char* Ab = (const char*)&As[c & 1][0];
        const char* Bb = (const char*)&Bs[c & 1][0];
        short8 a[4], b[4];
        #pragma unroll
        for (int ni = 0; ni < 4; ++ni) {
            b[ni] = *(const short8*)(Bb + (wc * 64 + ni * 16 + rl) * 64 + kread);
            a[ni] = *(const short8*)(Ab + (wr * 64 + ni * 16 + rl) * 64 + kread);
        }
        __builtin_amdgcn_s_setprio(1);
        #pragma unroll
        for (int mi = 0; mi < 4; ++mi)
            #pragma unroll
            for (int ni = 0; ni < 4; ++ni)
                acc[mi][ni] = __builtin_amdgcn_mfma_f32_16x16x32_bf16(
                    a[mi], b[ni], acc[mi][ni], 0, 0, 0);
        __builtin_amdgcn_s_setprio(0);
        // reads retired before MFMAs issued -> next top barrier closes this slot
    };

    stage_chunk(0);

    #pragma unroll 1
    for (int c = 0; c < NCH; ++c) {
        asm volatile("s_waitcnt vmcnt(0)" ::: "memory");   // chunk-c loads landed
        __builtin_amdgcn_s_barrier();
        asm volatile("" ::: "memory");
        if (c + 1 < NCH) stage_chunk(c + 1);               // depth-1 prefetch into other slot
        do_chunk(c);
    }

    // epilogue: partial sim over this block's 128 d-columns
    __syncthreads();
    #pragma unroll
    for (int mi = 0; mi < 4; ++mi) {
        #pragma unroll
        for (int r = 0; r < 4; ++r) {
            int Rl = wr * 64 + mi * 16 + g4 * 4 + r;
            size_t Rg = (size_t)r0 + Rl;
            float s = 0.f;
            #pragma unroll
            for (int ni = 0; ni < 4; ++ni) {
                int d = n0 + wc * 64 + ni * 16 + rl;
                s += acc[mi][ni][r] * b2f(Abf[Rg * CN + d]);
            }
            s += __shfl_xor(s, 1);
            s += __shfl_xor(s, 2);
            s += __shfl_xor(s, 4);
            s += __shfl_xor(s, 8);
            if (rl == 0) simpart[Rl * 3 + wc] = s;
        }
    }
    __syncthreads();
    if (t < 128) {
        float v = simpart[t * 3 + 0] + simpart[t * 3 + 1];
        atomicAdd(&simws[(size_t)w * MPAD2 + r0 + t], v);
    }
}

// ---------------- finish: act + conv dot + bias -> scores ----------------
__global__ void finish_kernel(const float* __restrict__ simws,
                              const float* __restrict__ conv_w,
                              const float* __restrict__ conv_b,
                              float* __restrict__ scores) {
    int q = blockIdx.x, w = blockIdx.y;
    int t = threadIdx.x;    // 128
    const float* sp = simws + (size_t)w * MPAD2 + q * HWN;
    float s = 0.f;
    for (int i = t; i < HWN; i += 128) {
        float v = sp[i];
        float a = (v >= 0.f) ? v : 0.2f * v;
        s += a * conv_w[i];
    }
    __shared__ float red[2];
    #pragma unroll
    for (int off = 32; off > 0; off >>= 1) s += __shfl_down(s, off);
    if ((t & 63) == 0) red[t >> 6] = s;
    __syncthreads();
    if (t == 0) scores[q * WAYN + w] = red[0] + red[1] + conv_b[0];
}

extern "C" void kernel_launch(void* const* d_in, const int* in_sizes, int n_in,
                              void* d_out, int out_size, void* d_ws, size_t ws_size,
                              hipStream_t stream) {
    const float* x1     = (const float*)d_in[0];
    const float* x2     = (const float*)d_in[1];
    const float* conv_w = (const float*)d_in[2];
    const float* conv_b = (const float*)d_in[3];
    float* scores = (float*)d_out;

    char* ws = (char*)d_ws;
    u16* covb    = (u16*)ws;                               // 2,621,440 B
    float* simws = (float*)(ws + 2631680);                 // 1,326,080 B
    float* covf  = (float*)(ws + 3957760);                 // 5,242,880 B
    // x2c aliases head of Abf (covmfma reads x2c before qtrans writes Abf)
    u16* x2c     = (u16*)(ws + 9200640);                   // 11,304,960 B
    u16* Abf     = (u16*)(ws + 9200640);                   // 66304*512*2 = 67,895,296 B

    wx2c_kernel<<<WAYN * CN, 64, 0, stream>>>(x2, x2c);
    init2_kernel<<<256, 256, 0, stream>>>(simws, covf, (u32*)(Abf + (size_t)MROWS * CN));
    covmfma_kernel<<<dim3(10, 1, WAYN * 3), 256, 0, stream>>>(x2c, covf);
    cov2b_kernel<<<WAYN * CN * CN / 256, 256, 0, stream>>>(covf, covb);
    qtrans_kernel<<<dim3(8, QN), 256, 0, stream>>>(x1, Abf);
    gemm128v_kernel<<<8 * 65 * 20, 256, 0, stream>>>(Abf, covb, simws);
    finish_kernel<<<dim3(QN, WAYN), 128, 0, stream>>>(simws, conv_w, conv_b, scores);
}